// Round 10
// baseline (233.827 us; speedup 1.0000x reference)
//
#include <hip/hip_runtime.h>
#include <hip/hip_fp16.h>

typedef unsigned int u32;

static inline size_t al16(size_t x){ return (x + 15) & ~(size_t)15; }

#define NPB 128            // nodes per bucket
#define PBSH 7
#define NBLK 64            // partition blocks (1024 thr): run len = E/(NBLK*NB) ~64 edges = 512B
#define SRCMSK 0xFFFFFu
#define STAGE_CAP 5120     // LDS staging capacity (edges) per bucket; avg ~4096

// A1: per-block LDS histogram of dst buckets. hist layout [blk][bucket].
__global__ void k_hist(const int* __restrict__ col, u32* __restrict__ hist,
                       int E, int NB, int chunk) {
  __shared__ u32 h[1024];
  int tid = threadIdx.x, blk = blockIdx.x;
  h[tid] = 0;
  __syncthreads();
  int e0 = blk * chunk, e1 = min(E, e0 + chunk);
  for (int e = e0 + tid; e < e1; e += 1024) atomicAdd(&h[col[e] >> PBSH], 1u);
  __syncthreads();
  for (int i = tid; i < NB; i += 1024) hist[(size_t)blk * NB + i] = h[i];
}

// A2a: per-bucket exclusive scan over the NBLK blocks -> hofs[bucket][blk]; totals.
__global__ void k_cscan(const u32* __restrict__ hist, u32* __restrict__ hofs,
                        u32* __restrict__ totals, int NB) {
  __shared__ u32 s[NBLK];
  int i = blockIdx.x, t = threadIdx.x;
  u32 v = hist[(size_t)t * NB + i];
  s[t] = v; __syncthreads();
  for (int off = 1; off < NBLK; off <<= 1) {
    u32 x = (t >= off) ? s[t - off] : 0u;
    __syncthreads(); s[t] += x; __syncthreads();
  }
  hofs[(size_t)i * NBLK + t] = s[t] - v;
  if (t == NBLK - 1) totals[i] = s[t];
}

// A2b: scan bucket totals -> bstart; sentinels.
__global__ void k_bscan(const u32* __restrict__ totals, u32* __restrict__ bstart,
                        u32* __restrict__ rowptr, int NB, int N, int E) {
  __shared__ u32 s[1024];
  int t = threadIdx.x;
  u32 v = (t < NB) ? totals[t] : 0u;
  s[t] = v; __syncthreads();
  for (int off = 1; off < 1024; off <<= 1) {
    u32 x = (t >= off) ? s[t - off] : 0u;
    __syncthreads(); s[t] += x; __syncthreads();
  }
  if (t < NB) bstart[t] = s[t] - v;
  if (t == 0) { bstart[NB] = (u32)E; rowptr[N] = (u32)E; }
}

// A3: scatter edges into bucket-contiguous records {src|dl<<20, w}. LDS cursors only.
__global__ void k_part(const int* __restrict__ row, const int* __restrict__ col,
                       const float* __restrict__ ew, const u32* __restrict__ bstart,
                       const u32* __restrict__ hofs, uint2* __restrict__ recs,
                       int E, int NB, int chunk) {
  __shared__ u32 cur[1024];
  int tid = threadIdx.x, blk = blockIdx.x;
  for (int i = tid; i < NB; i += 1024)
    cur[i] = bstart[i] + hofs[(size_t)i * NBLK + blk];
  __syncthreads();
  int e0 = blk * chunk, e1 = min(E, e0 + chunk);
  for (int e = e0 + tid; e < e1; e += 1024) {
    int c = col[e];
    int b = c >> PBSH;
    u32 dl = (u32)(c & (NPB - 1));
    u32 pos = atomicAdd(&cur[b], 1u);
    uint2 v; v.x = (u32)row[e] | (dl << 20); v.y = __float_as_uint(ew[e]);
    recs[pos] = v;
  }
}

// B: one block per bucket. count -> scan -> LDS-staged dl-sort -> COALESCED csr
// write-out (+rowptr). No f32 atomics; no partial-line global scatters.
__global__ void k_build(const uint2* __restrict__ recs, const u32* __restrict__ bstart,
                        u32* __restrict__ rowptr, uint2* __restrict__ csr, int N) {
  __shared__ uint2 stage[STAGE_CAP];
  __shared__ u32 cnt[NPB];
  __shared__ u32 sc[NPB];
  __shared__ u32 cur[NPB];
  int b = blockIdx.x, t = threadIdx.x;
  if (t < NPB) cnt[t] = 0;
  __syncthreads();
  u32 r0 = bstart[b], r1 = bstart[b + 1];
  int cap_ok = (r1 - r0) <= STAGE_CAP;
  for (u32 e = r0 + t; e < r1; e += 256) atomicAdd(&cnt[recs[e].x >> 20], 1u);
  __syncthreads();
  if (t < NPB) sc[t] = cnt[t];
  __syncthreads();
  for (int off = 1; off < NPB; off <<= 1) {
    u32 x = (t < NPB && t >= off) ? sc[t - off] : 0u;
    __syncthreads();
    if (t < NPB) sc[t] += x;
    __syncthreads();
  }
  if (t < NPB) {
    u32 excl = sc[t] - cnt[t];
    int node = (b << PBSH) + t;
    if (node < N) rowptr[node] = r0 + excl;
    cur[t] = excl;
  }
  __syncthreads();
  if (cap_ok) {
    for (u32 e = r0 + t; e < r1; e += 256) {
      uint2 v = recs[e];
      u32 dl = v.x >> 20;
      u32 slot = atomicAdd(&cur[dl], 1u);
      uint2 o; o.x = v.x & SRCMSK; o.y = v.y;
      stage[slot] = o;
    }
    __syncthreads();
    for (u32 i = t; i < r1 - r0; i += 256) csr[r0 + i] = stage[i];
  } else {
    for (u32 e = r0 + t; e < r1; e += 256) {
      uint2 v = recs[e];
      u32 dl = v.x >> 20;
      u32 slot = atomicAdd(&cur[dl], 1u);
      uint2 o; o.x = v.x & SRCMSK; o.y = v.y;
      csr[r0 + slot] = o;
    }
  }
}

// Weighted in-degree from CSR rows (sequential reads, shuffle reduce) -> dinv.
__global__ void k_deg(const uint2* __restrict__ csr, const u32* __restrict__ rowptr,
                      float* __restrict__ dinv, int n) {
  int tid = threadIdx.x;
  int g = tid >> 4, j = tid & 15;
  int node = blockIdx.x * 16 + g;
  if (node >= n) return;
  u32 e0 = rowptr[node], e1 = rowptr[node + 1];
  float s = 0.f;
  for (u32 e = e0 + j; e < e1; e += 16) s += __uint_as_float(csr[e].y);
  #pragma unroll
  for (int off = 8; off; off >>= 1) s += __shfl_down(s, off, 16);
  if (j == 0) dinv[node] = rsqrtf(s + 1.0f);  // +1 = self-loop weight
}

// ht1' = dinv[node] * (x @ W1), fp16 node-major (dinv-scale folded here: every
// downstream use of ht1[src] is w*dinv[src]*ht1[src]). Runs AFTER k_deg.
__global__ void k_gemm1(const float* __restrict__ x, const float* __restrict__ W1,
                        const float* __restrict__ dinv, __half* __restrict__ ht1, int n) {
  __shared__ float sw[2048];
  for (int i = threadIdx.x; i < 2048; i += blockDim.x) sw[i] = W1[i];
  __syncthreads();
  int node = blockIdx.x * blockDim.x + threadIdx.x;
  if (node >= n) return;
  const float4* xr = (const float4*)(x + (size_t)node * 128);
  float acc[16];
  #pragma unroll
  for (int j = 0; j < 16; j++) acc[j] = 0.f;
  #pragma unroll 4
  for (int k4 = 0; k4 < 32; k4++) {
    float4 xv = xr[k4];
    const float* wb = &sw[k4 * 64];
    #pragma unroll
    for (int j = 0; j < 16; j++) acc[j] += xv.x * wb[j];
    #pragma unroll
    for (int j = 0; j < 16; j++) acc[j] += xv.y * wb[16 + j];
    #pragma unroll
    for (int j = 0; j < 16; j++) acc[j] += xv.z * wb[32 + j];
    #pragma unroll
    for (int j = 0; j < 16; j++) acc[j] += xv.w * wb[48 + j];
  }
  float di = dinv[node];
  u32 o[8];
  #pragma unroll
  for (int p = 0; p < 8; p++) {
    u32 lo = (u32)__half_as_ushort(__float2half(di * acc[2 * p]));
    u32 hi = (u32)__half_as_ushort(__float2half(di * acc[2 * p + 1]));
    o[p] = lo | (hi << 16);
  }
  uint4* dst = (uint4*)(ht1 + (size_t)node * 16);
  dst[0] = make_uint4(o[0], o[1], o[2], o[3]);
  dst[1] = make_uint4(o[4], o[5], o[6], o[7]);
}

// Per-edge core: lane s owns channels 4s..4s+3; tables pre-scaled by dinv[node].
__device__ __forceinline__ void edge_sum4(const __half* __restrict__ ht,
                                          const uint2* __restrict__ csr,
                                          u32 e0, u32 e1, int s,
                                          float& a0, float& a1, float& a2, float& a3) {
  u32 e = e0;
  for (; e + 8 <= e1; e += 8) {
    uint2 v[8];
    #pragma unroll
    for (int t = 0; t < 8; t++) v[t] = csr[e + t];
    uint2 h[8];
    #pragma unroll
    for (int t = 0; t < 8; t++)
      h[t] = *(const uint2*)(ht + (size_t)v[t].x * 16 + s * 4);
    #pragma unroll
    for (int t = 0; t < 8; t++) {
      float w = __uint_as_float(v[t].y);
      float2 lo = __half22float2(*(__half2*)&h[t].x);
      float2 hi = __half22float2(*(__half2*)&h[t].y);
      a0 += w * lo.x; a1 += w * lo.y; a2 += w * hi.x; a3 += w * hi.y;
    }
  }
  for (; e < e1; e++) {
    uint2 v = csr[e];
    uint2 h = *(const uint2*)(ht + (size_t)v.x * 16 + s * 4);
    float w = __uint_as_float(v.y);
    float2 lo = __half22float2(*(__half2*)&h.x);
    float2 hi = __half22float2(*(__half2*)&h.y);
    a0 += w * lo.x; a1 += w * lo.y; a2 += w * hi.x; a3 += w * hi.y;
  }
}

// Conv1 agg + bias + relu, fused @W2; epilogue scales by dinv[node] for agg2's
// table (ht2' = dinv*(h1@W2)). Self term: di*(sum + ht1'[node]) since
// ht1' = dinv*xW1 already carries one dinv.
__global__ void k_agg1(const __half* __restrict__ ht1, const u32* __restrict__ rowptr,
                       const uint2* __restrict__ csr, const float* __restrict__ dinv,
                       const float* __restrict__ b1, const float* __restrict__ W2,
                       __half* __restrict__ ht2, int n) {
  __shared__ float sw2[256];
  __shared__ float sr[64][20];
  int tid = threadIdx.x;
  sw2[tid] = W2[tid];
  int g = tid >> 2, s = tid & 3;
  int node = blockIdx.x * 64 + g;
  float a0 = 0.f, a1 = 0.f, a2 = 0.f, a3 = 0.f;
  float di = 0.f;
  if (node < n) {
    u32 e0 = rowptr[node], e1 = rowptr[node + 1];
    edge_sum4(ht1, csr, e0, e1, s, a0, a1, a2, a3);
    di = dinv[node];
    uint2 hs = *(const uint2*)(ht1 + (size_t)node * 16 + s * 4);
    float2 slo = __half22float2(*(__half2*)&hs.x);
    float2 shi = __half22float2(*(__half2*)&hs.y);
    a0 = fmaxf(di * (a0 + slo.x) + b1[4 * s + 0], 0.f);
    a1 = fmaxf(di * (a1 + slo.y) + b1[4 * s + 1], 0.f);
    a2 = fmaxf(di * (a2 + shi.x) + b1[4 * s + 2], 0.f);
    a3 = fmaxf(di * (a3 + shi.y) + b1[4 * s + 3], 0.f);
  }
  *(float4*)&sr[g][4 * s] = make_float4(a0, a1, a2, a3);
  __syncthreads();
  if (node < n) {
    float o0 = 0.f, o1 = 0.f, o2 = 0.f, o3 = 0.f;
    #pragma unroll
    for (int k = 0; k < 16; k++) {
      float hk = sr[g][k];
      const float* wr = &sw2[k * 16 + 4 * s];
      o0 += hk * wr[0]; o1 += hk * wr[1]; o2 += hk * wr[2]; o3 += hk * wr[3];
    }
    __half2 p0 = __floats2half2_rn(di * o0, di * o1);
    __half2 p1 = __floats2half2_rn(di * o2, di * o3);
    uint2 st; st.x = *(u32*)&p0; st.y = *(u32*)&p1;
    *(uint2*)(ht2 + (size_t)node * 16 + 4 * s) = st;
  }
}

// Conv2 agg + bias, fused mean-pool partials (segmented LDS reduce + native f32 atomics).
__global__ void k_agg2(const __half* __restrict__ ht2, const u32* __restrict__ rowptr,
                       const uint2* __restrict__ csr, const float* __restrict__ dinv,
                       const float* __restrict__ b2, const int* __restrict__ batch,
                       float* __restrict__ pooled, int n) {
  __shared__ float sr[64][20];
  __shared__ int sbid[64];
  int tid = threadIdx.x;
  int g = tid >> 2, s = tid & 3;
  int node = blockIdx.x * 64 + g;
  float a0 = 0.f, a1 = 0.f, a2 = 0.f, a3 = 0.f;
  int myb = -1;
  if (node < n) {
    u32 e0 = rowptr[node], e1 = rowptr[node + 1];
    edge_sum4(ht2, csr, e0, e1, s, a0, a1, a2, a3);
    float di = dinv[node];
    uint2 hs = *(const uint2*)(ht2 + (size_t)node * 16 + s * 4);
    float2 slo = __half22float2(*(__half2*)&hs.x);
    float2 shi = __half22float2(*(__half2*)&hs.y);
    a0 = di * (a0 + slo.x) + b2[4 * s + 0];
    a1 = di * (a1 + slo.y) + b2[4 * s + 1];
    a2 = di * (a2 + shi.x) + b2[4 * s + 2];
    a3 = di * (a3 + shi.y) + b2[4 * s + 3];
    myb = batch[node];
  }
  *(float4*)&sr[g][4 * s] = make_float4(a0, a1, a2, a3);
  if (s == 0) sbid[g] = myb;
  __syncthreads();
  if (node < n) {
    bool head = (g == 0) || (sbid[g - 1] != myb);
    if (head) {
      float s0 = sr[g][4 * s + 0], s1 = sr[g][4 * s + 1];
      float s2 = sr[g][4 * s + 2], s3 = sr[g][4 * s + 3];
      for (int t = g + 1; t < 64 && sbid[t] == myb; t++) {
        s0 += sr[t][4 * s + 0]; s1 += sr[t][4 * s + 1];
        s2 += sr[t][4 * s + 2]; s3 += sr[t][4 * s + 3];
      }
      float* pb = &pooled[(size_t)myb * 16 + 4 * s];
      unsafeAtomicAdd(pb + 0, s0);
      unsafeAtomicAdd(pb + 1, s1);
      unsafeAtomicAdd(pb + 2, s2);
      unsafeAtomicAdd(pb + 3, s3);
    }
  }
}

// Mean + FC. Graph sizes via binary search on sorted batch.
__global__ void k_final(const float* __restrict__ pooled, const int* __restrict__ batch,
                        const float* __restrict__ fcW, const float* __restrict__ fcb,
                        float* __restrict__ out, int n, int G) {
  int g = blockIdx.x * blockDim.x + threadIdx.x;
  if (g >= G) return;
  int lo = 0, hi = n;
  while (lo < hi) { int m = (lo + hi) >> 1; if (batch[m] < g) lo = m + 1; else hi = m; }
  int lo2 = lo, hi2 = n;
  while (lo2 < hi2) { int m = (lo2 + hi2) >> 1; if (batch[m] < g + 1) lo2 = m + 1; else hi2 = m; }
  float c = (float)(lo2 - lo);
  float inv = 1.0f / fmaxf(c, 1.0f);
  float s = 0.f;
  #pragma unroll
  for (int j = 0; j < 16; j++) s += pooled[g * 16 + j] * fcW[j];
  out[g] = s * inv + fcb[0];
}

extern "C" void kernel_launch(void* const* d_in, const int* in_sizes, int n_in,
                              void* d_out, int out_size, void* d_ws, size_t ws_size,
                              hipStream_t stream) {
  const float* x    = (const float*)d_in[0];
  const int*   ei   = (const int*)d_in[1];
  const float* ew   = (const float*)d_in[2];
  const int*   batch= (const int*)d_in[3];
  const float* W1   = (const float*)d_in[4];
  const float* b1   = (const float*)d_in[5];
  const float* W2   = (const float*)d_in[6];
  const float* b2   = (const float*)d_in[7];
  const float* fcW  = (const float*)d_in[8];
  const float* fcb  = (const float*)d_in[9];
  float* out = (float*)d_out;

  int N = in_sizes[3];
  int E = in_sizes[2];
  int G = out_size;
  const int* row = ei;     // edge_index[0] = source
  const int* col = ei + E; // edge_index[1] = target

  int NB = (N + NPB - 1) >> PBSH;     // 128-node buckets (782 for N=100k)
  int chunk = (E + NBLK - 1) / NBLK;

  char* w = (char*)d_ws;
  size_t off = 0;
  auto alloc = [&](size_t bytes) -> char* { char* p = w + off; off = al16(off + bytes); return p; };
  u32*   hist   = (u32*)  alloc((size_t)NBLK * NB * 4);
  u32*   hofs   = (u32*)  alloc((size_t)NB * NBLK * 4);
  u32*   totals = (u32*)  alloc((size_t)NB * 4);
  u32*   bstart = (u32*)  alloc(((size_t)NB + 1) * 4);
  u32*   rowptr = (u32*)  alloc(((size_t)N + 1) * 4);
  float* dinv   = (float*)alloc((size_t)N * 4);
  uint2* recs   = (uint2*)alloc((size_t)E * 8);
  uint2* csr    = (uint2*)alloc((size_t)E * 8);
  float* pooled = (float*)alloc((size_t)G * 16 * 4);
  // recs dead after k_build: alias fp16 ht1/ht2 (gemm1 runs later).
  __half* ht1 = (__half*)recs;
  __half* ht2 = (__half*)((char*)recs + (size_t)N * 16 * 2);
  (void)n_in; (void)ws_size;

  hipMemsetAsync(pooled, 0, (size_t)G * 16 * 4, stream);

  int nb = (N + 255) / 256;
  int db = (N + 15) / 16;
  int ab = (N + 63) / 64;
  int gb = (G + 255) / 256;

  k_hist <<<NBLK, 1024, 0, stream>>>(col, hist, E, NB, chunk);
  k_cscan<<<NB, NBLK, 0, stream>>>(hist, hofs, totals, NB);
  k_bscan<<<1, 1024, 0, stream>>>(totals, bstart, rowptr, NB, N, E);
  k_part <<<NBLK, 1024, 0, stream>>>(row, col, ew, bstart, hofs, recs, E, NB, chunk);
  k_build<<<NB, 256, 0, stream>>>(recs, bstart, rowptr, csr, N);
  k_deg  <<<db, 256, 0, stream>>>(csr, rowptr, dinv, N);
  k_gemm1<<<nb, 256, 0, stream>>>(x, W1, dinv, ht1, N);
  k_agg1 <<<ab, 256, 0, stream>>>(ht1, rowptr, csr, dinv, b1, W2, ht2, N);
  k_agg2 <<<ab, 256, 0, stream>>>(ht2, rowptr, csr, dinv, b2, batch, pooled, N);
  k_final<<<gb, 256, 0, stream>>>(pooled, batch, fcW, fcb, out, N, G);
}

// Round 11
// 193.808 us; speedup vs baseline: 1.2065x; 1.2065x over previous
//
#include <hip/hip_runtime.h>
#include <hip/hip_fp16.h>

typedef unsigned int u32;

static inline size_t al16(size_t x){ return (x + 15) & ~(size_t)15; }

#define CSH 12             // 4096 nodes per coarse bucket
#define NBLK1 512          // level-1 partition blocks (512 thr): run = E/(512*25) ~250 edges
#define K2 16              // level-2 chunks per coarse region
#define FPB 32             // fine buckets per coarse (4096/128)
#define NPB 128            // nodes per fine bucket
#define PBSH 7
#define SRCMSK 0xFFFFFu
#define STAGE_CAP 5120     // LDS staging (edges) per fine bucket; avg ~4000

// L1 hist: per-block LDS histogram of coarse buckets. hist1 layout [blk][C].
__global__ void k_hist1(const int* __restrict__ col, u32* __restrict__ hist1,
                        int E, int C, int chunk) {
  __shared__ u32 h[64];
  int tid = threadIdx.x, blk = blockIdx.x;
  if (tid < 64) h[tid] = 0;
  __syncthreads();
  int e0 = blk * chunk, e1 = min(E, e0 + chunk);
  for (int e = e0 + tid; e < e1; e += 512) atomicAdd(&h[col[e] >> CSH], 1u);
  __syncthreads();
  if (tid < C) hist1[(size_t)blk * C + tid] = h[tid];
}

// L1 scan: per coarse bucket, exclusive scan over NBLK1 blocks.
__global__ void k_cscan1(const u32* __restrict__ hist1, u32* __restrict__ hofs1,
                         u32* __restrict__ totals1, int C) {
  __shared__ u32 s[NBLK1];
  int i = blockIdx.x, t = threadIdx.x;
  u32 v = hist1[(size_t)t * C + i];
  s[t] = v; __syncthreads();
  for (int off = 1; off < NBLK1; off <<= 1) {
    u32 x = (t >= off) ? s[t - off] : 0u;
    __syncthreads(); s[t] += x; __syncthreads();
  }
  hofs1[(size_t)i * NBLK1 + t] = s[t] - v;
  if (t == NBLK1 - 1) totals1[i] = s[t];
}

// L1 bucket-total scan (C<=64, trivial serial) + sentinels.
__global__ void k_bscan1(const u32* __restrict__ totals1, u32* __restrict__ bstart1,
                         u32* __restrict__ rowptr, int C, int N, int E) {
  if (threadIdx.x == 0) {
    u32 a = 0;
    for (int i = 0; i < C; i++) { bstart1[i] = a; a += totals1[i]; }
    bstart1[C] = (u32)E;
    rowptr[N] = (u32)E;
  }
}

// L1 scatter: {src | dl12<<20, w} into coarse-contiguous recs1. LDS cursors.
__global__ void k_part1(const int* __restrict__ row, const int* __restrict__ col,
                        const float* __restrict__ ew, const u32* __restrict__ bstart1,
                        const u32* __restrict__ hofs1, uint2* __restrict__ recs1,
                        int E, int C, int chunk) {
  __shared__ u32 cur[64];
  int tid = threadIdx.x, blk = blockIdx.x;
  if (tid < C) cur[tid] = bstart1[tid] + hofs1[(size_t)tid * NBLK1 + blk];
  __syncthreads();
  int e0 = blk * chunk, e1 = min(E, e0 + chunk);
  for (int e = e0 + tid; e < e1; e += 512) {
    int c = col[e];
    int cb = c >> CSH;
    u32 dl12 = (u32)(c & 4095);
    u32 pos = atomicAdd(&cur[cb], 1u);
    uint2 v; v.x = (u32)row[e] | (dl12 << 20); v.y = __float_as_uint(ew[e]);
    recs1[pos] = v;
  }
}

// L2 hist: block (cb,k) = chunk k of coarse region cb; 32 fine-bucket counters.
__global__ void k_hist2(const uint2* __restrict__ recs1, const u32* __restrict__ bstart1,
                        u32* __restrict__ cnt2) {
  __shared__ u32 h[FPB];
  int cb = blockIdx.x >> 4, k = blockIdx.x & 15;
  int t = threadIdx.x;
  if (t < FPB) h[t] = 0;
  __syncthreads();
  u32 r0 = bstart1[cb], r1 = bstart1[cb + 1];
  u32 len = r1 - r0, ch = (len + K2 - 1) / K2;
  u32 e0 = r0 + (u32)k * ch, e1 = min(r1, e0 + ch);
  for (u32 e = e0 + t; e < e1; e += 1024) atomicAdd(&h[recs1[e].x >> 27], 1u);
  __syncthreads();
  if (t < FPB) cnt2[((size_t)cb * K2 + k) * FPB + t] = h[t];
}

// L2 scan: per coarse bucket, scan (fine-major, chunk-minor) 512 values ->
// hofs2[cb][f][k], bstart2[cb*32+f].
__global__ void k_cscan2(const u32* __restrict__ cnt2, const u32* __restrict__ bstart1,
                         u32* __restrict__ hofs2, u32* __restrict__ bstart2,
                         int C, int E) {
  __shared__ u32 s[512];
  __shared__ u32 sx[512];
  int cb = blockIdx.x, t = threadIdx.x;
  int f = t >> 4, k = t & 15;
  u32 v = cnt2[((size_t)cb * K2 + k) * FPB + f];
  s[t] = v; __syncthreads();
  for (int off = 1; off < 512; off <<= 1) {
    u32 x = (t >= off) ? s[t - off] : 0u;
    __syncthreads(); s[t] += x; __syncthreads();
  }
  sx[t] = s[t] - v;
  __syncthreads();
  hofs2[((size_t)cb * FPB + f) * K2 + k] = sx[t] - sx[f << 4];
  if (k == 0) bstart2[cb * FPB + f] = bstart1[cb] + sx[t];
  if (cb == C - 1 && t == 0) bstart2[C * FPB] = (u32)E;
}

// L2 scatter: fine-bucket-contiguous recs2. 32 LDS cursors.
__global__ void k_part2(const uint2* __restrict__ recs1, const u32* __restrict__ bstart1,
                        const u32* __restrict__ hofs2, const u32* __restrict__ bstart2,
                        uint2* __restrict__ recs2) {
  __shared__ u32 cur[FPB];
  int cb = blockIdx.x >> 4, k = blockIdx.x & 15;
  int t = threadIdx.x;
  if (t < FPB) cur[t] = bstart2[cb * FPB + t] + hofs2[((size_t)cb * FPB + t) * K2 + k];
  __syncthreads();
  u32 r0 = bstart1[cb], r1 = bstart1[cb + 1];
  u32 len = r1 - r0, ch = (len + K2 - 1) / K2;
  u32 e0 = r0 + (u32)k * ch, e1 = min(r1, e0 + ch);
  for (u32 e = e0 + t; e < e1; e += 1024) {
    uint2 v = recs1[e];
    u32 pos = atomicAdd(&cur[v.x >> 27], 1u);
    recs2[pos] = v;
  }
}

// Build: one block per fine bucket. count -> scan -> LDS-staged sort ->
// coalesced csr write-out + rowptr.
__global__ void k_build(const uint2* __restrict__ recs2, const u32* __restrict__ bstart2,
                        u32* __restrict__ rowptr, uint2* __restrict__ csr, int N) {
  __shared__ uint2 stage[STAGE_CAP];
  __shared__ u32 cnt[NPB];
  __shared__ u32 sc[NPB];
  __shared__ u32 cur[NPB];
  int b = blockIdx.x, t = threadIdx.x;
  if (t < NPB) cnt[t] = 0;
  __syncthreads();
  u32 r0 = bstart2[b], r1 = bstart2[b + 1];
  int cap_ok = (r1 - r0) <= STAGE_CAP;
  for (u32 e = r0 + t; e < r1; e += 256) atomicAdd(&cnt[(recs2[e].x >> 20) & 127], 1u);
  __syncthreads();
  if (t < NPB) sc[t] = cnt[t];
  __syncthreads();
  for (int off = 1; off < NPB; off <<= 1) {
    u32 x = (t < NPB && t >= off) ? sc[t - off] : 0u;
    __syncthreads();
    if (t < NPB) sc[t] += x;
    __syncthreads();
  }
  if (t < NPB) {
    u32 excl = sc[t] - cnt[t];
    int node = (b << PBSH) + t;
    if (node < N) rowptr[node] = r0 + excl;
    cur[t] = excl;
  }
  __syncthreads();
  if (cap_ok) {
    for (u32 e = r0 + t; e < r1; e += 256) {
      uint2 v = recs2[e];
      u32 dl = (v.x >> 20) & 127;
      u32 slot = atomicAdd(&cur[dl], 1u);
      uint2 o; o.x = v.x & SRCMSK; o.y = v.y;
      stage[slot] = o;
    }
    __syncthreads();
    for (u32 i = t; i < r1 - r0; i += 256) csr[r0 + i] = stage[i];
  } else {
    for (u32 e = r0 + t; e < r1; e += 256) {
      uint2 v = recs2[e];
      u32 dl = (v.x >> 20) & 127;
      u32 slot = atomicAdd(&cur[dl], 1u);
      uint2 o; o.x = v.x & SRCMSK; o.y = v.y;
      csr[r0 + slot] = o;
    }
  }
}

// Weighted in-degree from CSR rows (sequential reads, shuffle reduce) -> dinv.
__global__ void k_deg(const uint2* __restrict__ csr, const u32* __restrict__ rowptr,
                      float* __restrict__ dinv, int n) {
  int tid = threadIdx.x;
  int g = tid >> 4, j = tid & 15;
  int node = blockIdx.x * 16 + g;
  if (node >= n) return;
  u32 e0 = rowptr[node], e1 = rowptr[node + 1];
  float s = 0.f;
  for (u32 e = e0 + j; e < e1; e += 16) s += __uint_as_float(csr[e].y);
  #pragma unroll
  for (int off = 8; off; off >>= 1) s += __shfl_down(s, off, 16);
  if (j == 0) dinv[node] = rsqrtf(s + 1.0f);  // +1 = self-loop weight
}

// ht1' = dinv[node] * (x @ W1), fp16 node-major (dinv folded; runs AFTER k_deg).
__global__ void k_gemm1(const float* __restrict__ x, const float* __restrict__ W1,
                        const float* __restrict__ dinv, __half* __restrict__ ht1, int n) {
  __shared__ float sw[2048];
  for (int i = threadIdx.x; i < 2048; i += blockDim.x) sw[i] = W1[i];
  __syncthreads();
  int node = blockIdx.x * blockDim.x + threadIdx.x;
  if (node >= n) return;
  const float4* xr = (const float4*)(x + (size_t)node * 128);
  float acc[16];
  #pragma unroll
  for (int j = 0; j < 16; j++) acc[j] = 0.f;
  #pragma unroll 4
  for (int k4 = 0; k4 < 32; k4++) {
    float4 xv = xr[k4];
    const float* wb = &sw[k4 * 64];
    #pragma unroll
    for (int j = 0; j < 16; j++) acc[j] += xv.x * wb[j];
    #pragma unroll
    for (int j = 0; j < 16; j++) acc[j] += xv.y * wb[16 + j];
    #pragma unroll
    for (int j = 0; j < 16; j++) acc[j] += xv.z * wb[32 + j];
    #pragma unroll
    for (int j = 0; j < 16; j++) acc[j] += xv.w * wb[48 + j];
  }
  float di = dinv[node];
  u32 o[8];
  #pragma unroll
  for (int p = 0; p < 8; p++) {
    u32 lo = (u32)__half_as_ushort(__float2half(di * acc[2 * p]));
    u32 hi = (u32)__half_as_ushort(__float2half(di * acc[2 * p + 1]));
    o[p] = lo | (hi << 16);
  }
  uint4* dst = (uint4*)(ht1 + (size_t)node * 16);
  dst[0] = make_uint4(o[0], o[1], o[2], o[3]);
  dst[1] = make_uint4(o[4], o[5], o[6], o[7]);
}

// Per-edge core: lane s owns channels 4s..4s+3; tables pre-scaled by dinv[node].
__device__ __forceinline__ void edge_sum4(const __half* __restrict__ ht,
                                          const uint2* __restrict__ csr,
                                          u32 e0, u32 e1, int s,
                                          float& a0, float& a1, float& a2, float& a3) {
  u32 e = e0;
  for (; e + 8 <= e1; e += 8) {
    uint2 v[8];
    #pragma unroll
    for (int t = 0; t < 8; t++) v[t] = csr[e + t];
    uint2 h[8];
    #pragma unroll
    for (int t = 0; t < 8; t++)
      h[t] = *(const uint2*)(ht + (size_t)v[t].x * 16 + s * 4);
    #pragma unroll
    for (int t = 0; t < 8; t++) {
      float w = __uint_as_float(v[t].y);
      float2 lo = __half22float2(*(__half2*)&h[t].x);
      float2 hi = __half22float2(*(__half2*)&h[t].y);
      a0 += w * lo.x; a1 += w * lo.y; a2 += w * hi.x; a3 += w * hi.y;
    }
  }
  for (; e < e1; e++) {
    uint2 v = csr[e];
    uint2 h = *(const uint2*)(ht + (size_t)v.x * 16 + s * 4);
    float w = __uint_as_float(v.y);
    float2 lo = __half22float2(*(__half2*)&h.x);
    float2 hi = __half22float2(*(__half2*)&h.y);
    a0 += w * lo.x; a1 += w * lo.y; a2 += w * hi.x; a3 += w * hi.y;
  }
}

// Conv1 agg + bias + relu, fused @W2; epilogue scales by dinv for agg2's table.
__global__ void k_agg1(const __half* __restrict__ ht1, const u32* __restrict__ rowptr,
                       const uint2* __restrict__ csr, const float* __restrict__ dinv,
                       const float* __restrict__ b1, const float* __restrict__ W2,
                       __half* __restrict__ ht2, int n) {
  __shared__ float sw2[256];
  __shared__ float sr[64][20];
  int tid = threadIdx.x;
  sw2[tid] = W2[tid];
  int g = tid >> 2, s = tid & 3;
  int node = blockIdx.x * 64 + g;
  float a0 = 0.f, a1 = 0.f, a2 = 0.f, a3 = 0.f;
  float di = 0.f;
  if (node < n) {
    u32 e0 = rowptr[node], e1 = rowptr[node + 1];
    edge_sum4(ht1, csr, e0, e1, s, a0, a1, a2, a3);
    di = dinv[node];
    uint2 hs = *(const uint2*)(ht1 + (size_t)node * 16 + s * 4);
    float2 slo = __half22float2(*(__half2*)&hs.x);
    float2 shi = __half22float2(*(__half2*)&hs.y);
    a0 = fmaxf(di * (a0 + slo.x) + b1[4 * s + 0], 0.f);
    a1 = fmaxf(di * (a1 + slo.y) + b1[4 * s + 1], 0.f);
    a2 = fmaxf(di * (a2 + shi.x) + b1[4 * s + 2], 0.f);
    a3 = fmaxf(di * (a3 + shi.y) + b1[4 * s + 3], 0.f);
  }
  *(float4*)&sr[g][4 * s] = make_float4(a0, a1, a2, a3);
  __syncthreads();
  if (node < n) {
    float o0 = 0.f, o1 = 0.f, o2 = 0.f, o3 = 0.f;
    #pragma unroll
    for (int k = 0; k < 16; k++) {
      float hk = sr[g][k];
      const float* wr = &sw2[k * 16 + 4 * s];
      o0 += hk * wr[0]; o1 += hk * wr[1]; o2 += hk * wr[2]; o3 += hk * wr[3];
    }
    __half2 p0 = __floats2half2_rn(di * o0, di * o1);
    __half2 p1 = __floats2half2_rn(di * o2, di * o3);
    uint2 st; st.x = *(u32*)&p0; st.y = *(u32*)&p1;
    *(uint2*)(ht2 + (size_t)node * 16 + 4 * s) = st;
  }
}

// Conv2 agg + bias, fused mean-pool partials (segmented LDS reduce + native f32 atomics).
__global__ void k_agg2(const __half* __restrict__ ht2, const u32* __restrict__ rowptr,
                       const uint2* __restrict__ csr, const float* __restrict__ dinv,
                       const float* __restrict__ b2, const int* __restrict__ batch,
                       float* __restrict__ pooled, int n) {
  __shared__ float sr[64][20];
  __shared__ int sbid[64];
  int tid = threadIdx.x;
  int g = tid >> 2, s = tid & 3;
  int node = blockIdx.x * 64 + g;
  float a0 = 0.f, a1 = 0.f, a2 = 0.f, a3 = 0.f;
  int myb = -1;
  if (node < n) {
    u32 e0 = rowptr[node], e1 = rowptr[node + 1];
    edge_sum4(ht2, csr, e0, e1, s, a0, a1, a2, a3);
    float di = dinv[node];
    uint2 hs = *(const uint2*)(ht2 + (size_t)node * 16 + s * 4);
    float2 slo = __half22float2(*(__half2*)&hs.x);
    float2 shi = __half22float2(*(__half2*)&hs.y);
    a0 = di * (a0 + slo.x) + b2[4 * s + 0];
    a1 = di * (a1 + slo.y) + b2[4 * s + 1];
    a2 = di * (a2 + shi.x) + b2[4 * s + 2];
    a3 = di * (a3 + shi.y) + b2[4 * s + 3];
    myb = batch[node];
  }
  *(float4*)&sr[g][4 * s] = make_float4(a0, a1, a2, a3);
  if (s == 0) sbid[g] = myb;
  __syncthreads();
  if (node < n) {
    bool head = (g == 0) || (sbid[g - 1] != myb);
    if (head) {
      float s0 = sr[g][4 * s + 0], s1 = sr[g][4 * s + 1];
      float s2 = sr[g][4 * s + 2], s3 = sr[g][4 * s + 3];
      for (int t = g + 1; t < 64 && sbid[t] == myb; t++) {
        s0 += sr[t][4 * s + 0]; s1 += sr[t][4 * s + 1];
        s2 += sr[t][4 * s + 2]; s3 += sr[t][4 * s + 3];
      }
      float* pb = &pooled[(size_t)myb * 16 + 4 * s];
      unsafeAtomicAdd(pb + 0, s0);
      unsafeAtomicAdd(pb + 1, s1);
      unsafeAtomicAdd(pb + 2, s2);
      unsafeAtomicAdd(pb + 3, s3);
    }
  }
}

// Mean + FC. Graph sizes via binary search on sorted batch.
__global__ void k_final(const float* __restrict__ pooled, const int* __restrict__ batch,
                        const float* __restrict__ fcW, const float* __restrict__ fcb,
                        float* __restrict__ out, int n, int G) {
  int g = blockIdx.x * blockDim.x + threadIdx.x;
  if (g >= G) return;
  int lo = 0, hi = n;
  while (lo < hi) { int m = (lo + hi) >> 1; if (batch[m] < g) lo = m + 1; else hi = m; }
  int lo2 = lo, hi2 = n;
  while (lo2 < hi2) { int m = (lo2 + hi2) >> 1; if (batch[m] < g + 1) lo2 = m + 1; else hi2 = m; }
  float c = (float)(lo2 - lo);
  float inv = 1.0f / fmaxf(c, 1.0f);
  float s = 0.f;
  #pragma unroll
  for (int j = 0; j < 16; j++) s += pooled[g * 16 + j] * fcW[j];
  out[g] = s * inv + fcb[0];
}

extern "C" void kernel_launch(void* const* d_in, const int* in_sizes, int n_in,
                              void* d_out, int out_size, void* d_ws, size_t ws_size,
                              hipStream_t stream) {
  const float* x    = (const float*)d_in[0];
  const int*   ei   = (const int*)d_in[1];
  const float* ew   = (const float*)d_in[2];
  const int*   batch= (const int*)d_in[3];
  const float* W1   = (const float*)d_in[4];
  const float* b1   = (const float*)d_in[5];
  const float* W2   = (const float*)d_in[6];
  const float* b2   = (const float*)d_in[7];
  const float* fcW  = (const float*)d_in[8];
  const float* fcb  = (const float*)d_in[9];
  float* out = (float*)d_out;

  int N = in_sizes[3];
  int E = in_sizes[2];
  int G = out_size;
  const int* row = ei;     // edge_index[0] = source
  const int* col = ei + E; // edge_index[1] = target

  int C   = (N + 4095) >> CSH;   // 25 coarse buckets
  int NBF = C * FPB;             // 800 fine buckets
  int chunk1 = (E + NBLK1 - 1) / NBLK1;

  char* w = (char*)d_ws;
  size_t off = 0;
  auto alloc = [&](size_t bytes) -> char* { char* p = w + off; off = al16(off + bytes); return p; };
  u32*   hist1   = (u32*)  alloc((size_t)NBLK1 * C * 4);
  u32*   hofs1   = (u32*)  alloc((size_t)C * NBLK1 * 4);
  u32*   totals1 = (u32*)  alloc((size_t)C * 4);
  u32*   bstart1 = (u32*)  alloc(((size_t)C + 1) * 4);
  u32*   cnt2    = (u32*)  alloc((size_t)C * K2 * FPB * 4);
  u32*   hofs2   = (u32*)  alloc((size_t)C * FPB * K2 * 4);
  u32*   bstart2 = (u32*)  alloc(((size_t)NBF + 1) * 4);
  u32*   rowptr  = (u32*)  alloc(((size_t)N + 1) * 4);
  float* dinv    = (float*)alloc((size_t)N * 4);
  uint2* recs1   = (uint2*)alloc((size_t)E * 8);
  uint2* recs2   = (uint2*)alloc((size_t)E * 8);
  float* pooled  = (float*)alloc((size_t)G * 16 * 4);
  // Aliases: csr overlays recs1 (dead after part2); ht1/ht2 overlay recs2 (dead after build).
  uint2*  csr = recs1;
  __half* ht1 = (__half*)recs2;
  __half* ht2 = (__half*)((char*)recs2 + (size_t)N * 16 * 2);
  (void)n_in; (void)ws_size;

  hipMemsetAsync(pooled, 0, (size_t)G * 16 * 4, stream);

  int nb = (N + 255) / 256;
  int db = (N + 15) / 16;
  int ab = (N + 63) / 64;
  int gb = (G + 255) / 256;

  k_hist1 <<<NBLK1, 512, 0, stream>>>(col, hist1, E, C, chunk1);
  k_cscan1<<<C, NBLK1, 0, stream>>>(hist1, hofs1, totals1, C);
  k_bscan1<<<1, 64, 0, stream>>>(totals1, bstart1, rowptr, C, N, E);
  k_part1 <<<NBLK1, 512, 0, stream>>>(row, col, ew, bstart1, hofs1, recs1, E, C, chunk1);
  k_hist2 <<<C * K2, 1024, 0, stream>>>(recs1, bstart1, cnt2);
  k_cscan2<<<C, 512, 0, stream>>>(cnt2, bstart1, hofs2, bstart2, C, E);
  k_part2 <<<C * K2, 1024, 0, stream>>>(recs1, bstart1, hofs2, bstart2, recs2);
  k_build <<<NBF, 256, 0, stream>>>(recs2, bstart2, rowptr, csr, N);
  k_deg   <<<db, 256, 0, stream>>>(csr, rowptr, dinv, N);
  k_gemm1 <<<nb, 256, 0, stream>>>(x, W1, dinv, ht1, N);
  k_agg1  <<<ab, 256, 0, stream>>>(ht1, rowptr, csr, dinv, b1, W2, ht2, N);
  k_agg2  <<<ab, 256, 0, stream>>>(ht2, rowptr, csr, dinv, b2, batch, pooled, N);
  k_final <<<gb, 256, 0, stream>>>(pooled, batch, fcW, fcb, out, N, G);
}

// Round 12
// 167.567 us; speedup vs baseline: 1.3954x; 1.1566x over previous
//
#include <hip/hip_runtime.h>
#include <hip/hip_fp16.h>

typedef unsigned int u32;

static inline size_t al16(size_t x){ return (x + 15) & ~(size_t)15; }

#define CSH 12             // 4096 nodes per coarse bucket
#define NBLK1 512          // level-1 partition blocks (512 thr): run = E/(512*25) ~250 edges
#define K2 16              // level-2 chunks per coarse region
#define FPB 32             // fine buckets per coarse (4096/128)
#define NPB 128            // nodes per fine bucket
#define PBSH 7
#define SRCMSK 0xFFFFFu
#define STAGE_CAP 5120     // LDS staging (edges) per fine bucket; avg ~4000, std ~63 -> never overflows

// L1 hist: per-block LDS histogram of coarse buckets. hist1 layout [blk][C].
__global__ void k_hist1(const int* __restrict__ col, u32* __restrict__ hist1,
                        int E, int C, int chunk) {
  __shared__ u32 h[64];
  int tid = threadIdx.x, blk = blockIdx.x;
  if (tid < 64) h[tid] = 0;
  __syncthreads();
  int e0 = blk * chunk, e1 = min(E, e0 + chunk);
  for (int e = e0 + tid; e < e1; e += 512) atomicAdd(&h[col[e] >> CSH], 1u);
  __syncthreads();
  if (tid < C) hist1[(size_t)blk * C + tid] = h[tid];
}

// L1 scan: per coarse bucket, exclusive scan over NBLK1 blocks.
__global__ void k_cscan1(const u32* __restrict__ hist1, u32* __restrict__ hofs1,
                         u32* __restrict__ totals1, int C) {
  __shared__ u32 s[NBLK1];
  int i = blockIdx.x, t = threadIdx.x;
  u32 v = hist1[(size_t)t * C + i];
  s[t] = v; __syncthreads();
  for (int off = 1; off < NBLK1; off <<= 1) {
    u32 x = (t >= off) ? s[t - off] : 0u;
    __syncthreads(); s[t] += x; __syncthreads();
  }
  hofs1[(size_t)i * NBLK1 + t] = s[t] - v;
  if (t == NBLK1 - 1) totals1[i] = s[t];
}

// L1 bucket-total scan (C<=64, trivial serial) + sentinels.
__global__ void k_bscan1(const u32* __restrict__ totals1, u32* __restrict__ bstart1,
                         u32* __restrict__ rowptr, int C, int N, int E) {
  if (threadIdx.x == 0) {
    u32 a = 0;
    for (int i = 0; i < C; i++) { bstart1[i] = a; a += totals1[i]; }
    bstart1[C] = (u32)E;
    rowptr[N] = (u32)E;
  }
}

// L1 scatter: {src | dl12<<20, w} into coarse-contiguous recs1. LDS cursors.
__global__ void k_part1(const int* __restrict__ row, const int* __restrict__ col,
                        const float* __restrict__ ew, const u32* __restrict__ bstart1,
                        const u32* __restrict__ hofs1, uint2* __restrict__ recs1,
                        int E, int C, int chunk) {
  __shared__ u32 cur[64];
  int tid = threadIdx.x, blk = blockIdx.x;
  if (tid < C) cur[tid] = bstart1[tid] + hofs1[(size_t)tid * NBLK1 + blk];
  __syncthreads();
  int e0 = blk * chunk, e1 = min(E, e0 + chunk);
  for (int e = e0 + tid; e < e1; e += 512) {
    int c = col[e];
    int cb = c >> CSH;
    u32 dl12 = (u32)(c & 4095);
    u32 pos = atomicAdd(&cur[cb], 1u);
    uint2 v; v.x = (u32)row[e] | (dl12 << 20); v.y = __float_as_uint(ew[e]);
    recs1[pos] = v;
  }
}

// L2 hist: block (cb,k) = chunk k of coarse region cb; 32 fine-bucket counters.
__global__ void k_hist2(const uint2* __restrict__ recs1, const u32* __restrict__ bstart1,
                        u32* __restrict__ cnt2) {
  __shared__ u32 h[FPB];
  int cb = blockIdx.x >> 4, k = blockIdx.x & 15;
  int t = threadIdx.x;
  if (t < FPB) h[t] = 0;
  __syncthreads();
  u32 r0 = bstart1[cb], r1 = bstart1[cb + 1];
  u32 len = r1 - r0, ch = (len + K2 - 1) / K2;
  u32 e0 = r0 + (u32)k * ch, e1 = min(r1, e0 + ch);
  for (u32 e = e0 + t; e < e1; e += 1024) atomicAdd(&h[recs1[e].x >> 27], 1u);
  __syncthreads();
  if (t < FPB) cnt2[((size_t)cb * K2 + k) * FPB + t] = h[t];
}

// L2 scan: per coarse bucket, scan (fine-major, chunk-minor) 512 values ->
// hofs2[cb][f][k], bstart2[cb*32+f].
__global__ void k_cscan2(const u32* __restrict__ cnt2, const u32* __restrict__ bstart1,
                         u32* __restrict__ hofs2, u32* __restrict__ bstart2,
                         int C, int E) {
  __shared__ u32 s[512];
  __shared__ u32 sx[512];
  int cb = blockIdx.x, t = threadIdx.x;
  int f = t >> 4, k = t & 15;
  u32 v = cnt2[((size_t)cb * K2 + k) * FPB + f];
  s[t] = v; __syncthreads();
  for (int off = 1; off < 512; off <<= 1) {
    u32 x = (t >= off) ? s[t - off] : 0u;
    __syncthreads(); s[t] += x; __syncthreads();
  }
  sx[t] = s[t] - v;
  __syncthreads();
  hofs2[((size_t)cb * FPB + f) * K2 + k] = sx[t] - sx[f << 4];
  if (k == 0) bstart2[cb * FPB + f] = bstart1[cb] + sx[t];
  if (cb == C - 1 && t == 0) bstart2[C * FPB] = (u32)E;
}

// L2 scatter: fine-bucket-contiguous recs2. 32 LDS cursors.
__global__ void k_part2(const uint2* __restrict__ recs1, const u32* __restrict__ bstart1,
                        const u32* __restrict__ hofs2, const u32* __restrict__ bstart2,
                        uint2* __restrict__ recs2) {
  __shared__ u32 cur[FPB];
  int cb = blockIdx.x >> 4, k = blockIdx.x & 15;
  int t = threadIdx.x;
  if (t < FPB) cur[t] = bstart2[cb * FPB + t] + hofs2[((size_t)cb * FPB + t) * K2 + k];
  __syncthreads();
  u32 r0 = bstart1[cb], r1 = bstart1[cb + 1];
  u32 len = r1 - r0, ch = (len + K2 - 1) / K2;
  u32 e0 = r0 + (u32)k * ch, e1 = min(r1, e0 + ch);
  for (u32 e = e0 + t; e < e1; e += 1024) {
    uint2 v = recs1[e];
    u32 pos = atomicAdd(&cur[v.x >> 27], 1u);
    recs2[pos] = v;
  }
}

// Build: one block per fine bucket. count -> scan -> LDS-staged sort ->
// coalesced csr write-out + rowptr + FUSED weighted-degree -> dinv.
__global__ void k_build(const uint2* __restrict__ recs2, const u32* __restrict__ bstart2,
                        u32* __restrict__ rowptr, uint2* __restrict__ csr,
                        float* __restrict__ dinv, int N) {
  __shared__ uint2 stage[STAGE_CAP];
  __shared__ u32 cnt[NPB];
  __shared__ u32 sc[NPB];
  __shared__ u32 cur[NPB];
  int b = blockIdx.x, t = threadIdx.x;
  if (t < NPB) cnt[t] = 0;
  __syncthreads();
  u32 r0 = bstart2[b], r1 = bstart2[b + 1];
  int cap_ok = (r1 - r0) <= STAGE_CAP;
  for (u32 e = r0 + t; e < r1; e += 256) atomicAdd(&cnt[(recs2[e].x >> 20) & 127], 1u);
  __syncthreads();
  if (t < NPB) sc[t] = cnt[t];
  __syncthreads();
  for (int off = 1; off < NPB; off <<= 1) {
    u32 x = (t < NPB && t >= off) ? sc[t - off] : 0u;
    __syncthreads();
    if (t < NPB) sc[t] += x;
    __syncthreads();
  }
  if (t < NPB) {
    u32 excl = sc[t] - cnt[t];
    int node = (b << PBSH) + t;
    if (node < N) rowptr[node] = r0 + excl;
    cur[t] = excl;
  }
  __syncthreads();
  if (cap_ok) {
    for (u32 e = r0 + t; e < r1; e += 256) {
      uint2 v = recs2[e];
      u32 dl = (v.x >> 20) & 127;
      u32 slot = atomicAdd(&cur[dl], 1u);
      uint2 o; o.x = v.x & SRCMSK; o.y = v.y;
      stage[slot] = o;
    }
    __syncthreads();
    for (u32 i = t; i < r1 - r0; i += 256) csr[r0 + i] = stage[i];
    // fused deg: node t's edges are stage[excl .. excl+cnt)
    if (t < NPB) {
      int node = (b << PBSH) + t;
      if (node < N) {
        u32 base = sc[t] - cnt[t], c = cnt[t];
        float sd = 0.f;
        for (u32 i = 0; i < c; i++) sd += __uint_as_float(stage[base + i].y);
        dinv[node] = rsqrtf(sd + 1.0f);   // +1 = self-loop weight
      }
    }
  } else {
    for (u32 e = r0 + t; e < r1; e += 256) {
      uint2 v = recs2[e];
      u32 dl = (v.x >> 20) & 127;
      u32 slot = atomicAdd(&cur[dl], 1u);
      uint2 o; o.x = v.x & SRCMSK; o.y = v.y;
      csr[r0 + slot] = o;
    }
    __syncthreads();
    if (t < NPB) {
      int node = (b << PBSH) + t;
      if (node < N) {
        u32 base = r0 + sc[t] - cnt[t], c = cnt[t];
        float sd = 0.f;
        for (u32 i = 0; i < c; i++) sd += __uint_as_float(csr[base + i].y);
        dinv[node] = rsqrtf(sd + 1.0f);
      }
    }
  }
}

// ht1' = dinv[node] * (x @ W1), fp16 node-major (dinv folded; runs AFTER build).
__global__ void k_gemm1(const float* __restrict__ x, const float* __restrict__ W1,
                        const float* __restrict__ dinv, __half* __restrict__ ht1, int n) {
  __shared__ float sw[2048];
  for (int i = threadIdx.x; i < 2048; i += blockDim.x) sw[i] = W1[i];
  __syncthreads();
  int node = blockIdx.x * blockDim.x + threadIdx.x;
  if (node >= n) return;
  const float4* xr = (const float4*)(x + (size_t)node * 128);
  float acc[16];
  #pragma unroll
  for (int j = 0; j < 16; j++) acc[j] = 0.f;
  #pragma unroll 4
  for (int k4 = 0; k4 < 32; k4++) {
    float4 xv = xr[k4];
    const float* wb = &sw[k4 * 64];
    #pragma unroll
    for (int j = 0; j < 16; j++) acc[j] += xv.x * wb[j];
    #pragma unroll
    for (int j = 0; j < 16; j++) acc[j] += xv.y * wb[16 + j];
    #pragma unroll
    for (int j = 0; j < 16; j++) acc[j] += xv.z * wb[32 + j];
    #pragma unroll
    for (int j = 0; j < 16; j++) acc[j] += xv.w * wb[48 + j];
  }
  float di = dinv[node];
  u32 o[8];
  #pragma unroll
  for (int p = 0; p < 8; p++) {
    u32 lo = (u32)__half_as_ushort(__float2half(di * acc[2 * p]));
    u32 hi = (u32)__half_as_ushort(__float2half(di * acc[2 * p + 1]));
    o[p] = lo | (hi << 16);
  }
  uint4* dst = (uint4*)(ht1 + (size_t)node * 16);
  dst[0] = make_uint4(o[0], o[1], o[2], o[3]);
  dst[1] = make_uint4(o[4], o[5], o[6], o[7]);
}

// Per-edge core, 8 lanes/node: lane s owns channels {2s,2s+1}. Per 8-edge batch,
// lane s loads csr[e+s] (coalesced, 1 line/group) and {src,w} are distributed
// via width-8 shuffles; each lane gathers its 4B of the 32B ht row. Tail edges
// padded with w=0 (src=0 gather harmless).
__device__ __forceinline__ void edge_sum2(const __half* __restrict__ ht,
                                          const uint2* __restrict__ csr,
                                          u32 e0, u32 e1, int s,
                                          float& a0, float& a1) {
  for (u32 e = e0; e < e1; e += 8) {
    u32 idx = e + (u32)s;
    uint2 r = (idx < e1) ? csr[idx] : make_uint2(0u, 0u);
    #pragma unroll
    for (int t = 0; t < 8; t++) {
      u32 srct = (u32)__shfl((int)r.x, t, 8);
      float wt = __uint_as_float((u32)__shfl((int)r.y, t, 8));
      u32 hw = *(const u32*)((const char*)ht + (size_t)srct * 32 + s * 4);
      float2 hf = __half22float2(*(__half2*)&hw);
      a0 += wt * hf.x;
      a1 += wt * hf.y;
    }
  }
}

// Conv1 agg + bias + relu, fused @W2; epilogue scales by dinv for agg2's table.
// 8 lanes/node, 32 nodes per 256-thread block.
__global__ void k_agg1(const __half* __restrict__ ht1, const u32* __restrict__ rowptr,
                       const uint2* __restrict__ csr, const float* __restrict__ dinv,
                       const float* __restrict__ b1, const float* __restrict__ W2,
                       __half* __restrict__ ht2, int n) {
  __shared__ float sw2[256];
  __shared__ float sr[32][18];
  int tid = threadIdx.x;
  sw2[tid] = W2[tid];
  int g = tid >> 3, s = tid & 7;
  int node = blockIdx.x * 32 + g;
  float a0 = 0.f, a1 = 0.f, di = 0.f;
  if (node < n) {
    u32 e0 = rowptr[node], e1 = rowptr[node + 1];
    edge_sum2(ht1, csr, e0, e1, s, a0, a1);
    di = dinv[node];
    u32 hs = *(const u32*)((const char*)ht1 + (size_t)node * 32 + s * 4);
    float2 sf = __half22float2(*(__half2*)&hs);
    a0 = fmaxf(di * (a0 + sf.x) + b1[2 * s + 0], 0.f);
    a1 = fmaxf(di * (a1 + sf.y) + b1[2 * s + 1], 0.f);
  }
  sr[g][2 * s] = a0; sr[g][2 * s + 1] = a1;
  __syncthreads();
  if (node < n) {
    float o0 = 0.f, o1 = 0.f;
    #pragma unroll
    for (int k = 0; k < 16; k++) {
      float hk = sr[g][k];
      o0 += hk * sw2[k * 16 + 2 * s];
      o1 += hk * sw2[k * 16 + 2 * s + 1];
    }
    __half2 p = __floats2half2_rn(di * o0, di * o1);
    *(u32*)((char*)ht2 + (size_t)node * 32 + s * 4) = *(u32*)&p;
  }
}

// Conv2 agg + bias, fused mean-pool partials (segmented LDS reduce + native f32 atomics).
__global__ void k_agg2(const __half* __restrict__ ht2, const u32* __restrict__ rowptr,
                       const uint2* __restrict__ csr, const float* __restrict__ dinv,
                       const float* __restrict__ b2, const int* __restrict__ batch,
                       float* __restrict__ pooled, int n) {
  __shared__ float sr[32][18];
  __shared__ int sbid[32];
  int tid = threadIdx.x;
  int g = tid >> 3, s = tid & 7;
  int node = blockIdx.x * 32 + g;
  float a0 = 0.f, a1 = 0.f;
  int myb = -1;
  if (node < n) {
    u32 e0 = rowptr[node], e1 = rowptr[node + 1];
    edge_sum2(ht2, csr, e0, e1, s, a0, a1);
    float di = dinv[node];
    u32 hs = *(const u32*)((const char*)ht2 + (size_t)node * 32 + s * 4);
    float2 sf = __half22float2(*(__half2*)&hs);
    a0 = di * (a0 + sf.x) + b2[2 * s + 0];
    a1 = di * (a1 + sf.y) + b2[2 * s + 1];
    myb = batch[node];
  }
  sr[g][2 * s] = a0; sr[g][2 * s + 1] = a1;
  if (s == 0) sbid[g] = myb;
  __syncthreads();
  if (node < n) {
    bool head = (g == 0) || (sbid[g - 1] != myb);
    if (head) {
      float s0 = a0, s1 = a1;
      for (int t = g + 1; t < 32 && sbid[t] == myb; t++) {
        s0 += sr[t][2 * s]; s1 += sr[t][2 * s + 1];
      }
      float* pb = &pooled[(size_t)myb * 16 + 2 * s];
      unsafeAtomicAdd(pb + 0, s0);
      unsafeAtomicAdd(pb + 1, s1);
    }
  }
}

// Mean + FC. Graph sizes via binary search on sorted batch.
__global__ void k_final(const float* __restrict__ pooled, const int* __restrict__ batch,
                        const float* __restrict__ fcW, const float* __restrict__ fcb,
                        float* __restrict__ out, int n, int G) {
  int g = blockIdx.x * blockDim.x + threadIdx.x;
  if (g >= G) return;
  int lo = 0, hi = n;
  while (lo < hi) { int m = (lo + hi) >> 1; if (batch[m] < g) lo = m + 1; else hi = m; }
  int lo2 = lo, hi2 = n;
  while (lo2 < hi2) { int m = (lo2 + hi2) >> 1; if (batch[m] < g + 1) lo2 = m + 1; else hi2 = m; }
  float c = (float)(lo2 - lo);
  float inv = 1.0f / fmaxf(c, 1.0f);
  float s = 0.f;
  #pragma unroll
  for (int j = 0; j < 16; j++) s += pooled[g * 16 + j] * fcW[j];
  out[g] = s * inv + fcb[0];
}

extern "C" void kernel_launch(void* const* d_in, const int* in_sizes, int n_in,
                              void* d_out, int out_size, void* d_ws, size_t ws_size,
                              hipStream_t stream) {
  const float* x    = (const float*)d_in[0];
  const int*   ei   = (const int*)d_in[1];
  const float* ew   = (const float*)d_in[2];
  const int*   batch= (const int*)d_in[3];
  const float* W1   = (const float*)d_in[4];
  const float* b1   = (const float*)d_in[5];
  const float* W2   = (const float*)d_in[6];
  const float* b2   = (const float*)d_in[7];
  const float* fcW  = (const float*)d_in[8];
  const float* fcb  = (const float*)d_in[9];
  float* out = (float*)d_out;

  int N = in_sizes[3];
  int E = in_sizes[2];
  int G = out_size;
  const int* row = ei;     // edge_index[0] = source
  const int* col = ei + E; // edge_index[1] = target

  int C   = (N + 4095) >> CSH;   // 25 coarse buckets
  int NBF = C * FPB;             // 800 fine buckets
  int chunk1 = (E + NBLK1 - 1) / NBLK1;

  char* w = (char*)d_ws;
  size_t off = 0;
  auto alloc = [&](size_t bytes) -> char* { char* p = w + off; off = al16(off + bytes); return p; };
  u32*   hist1   = (u32*)  alloc((size_t)NBLK1 * C * 4);
  u32*   hofs1   = (u32*)  alloc((size_t)C * NBLK1 * 4);
  u32*   totals1 = (u32*)  alloc((size_t)C * 4);
  u32*   bstart1 = (u32*)  alloc(((size_t)C + 1) * 4);
  u32*   cnt2    = (u32*)  alloc((size_t)C * K2 * FPB * 4);
  u32*   hofs2   = (u32*)  alloc((size_t)C * FPB * K2 * 4);
  u32*   bstart2 = (u32*)  alloc(((size_t)NBF + 1) * 4);
  u32*   rowptr  = (u32*)  alloc(((size_t)N + 1) * 4);
  float* dinv    = (float*)alloc((size_t)N * 4);
  uint2* recs1   = (uint2*)alloc((size_t)E * 8);
  uint2* recs2   = (uint2*)alloc((size_t)E * 8);
  float* pooled  = (float*)alloc((size_t)G * 16 * 4);
  // Aliases: csr overlays recs1 (dead after part2); ht1/ht2 overlay recs2 (dead after build).
  uint2*  csr = recs1;
  __half* ht1 = (__half*)recs2;
  __half* ht2 = (__half*)((char*)recs2 + (size_t)N * 16 * 2);
  (void)n_in; (void)ws_size;

  hipMemsetAsync(pooled, 0, (size_t)G * 16 * 4, stream);

  int nb = (N + 255) / 256;
  int ab = (N + 31) / 32;
  int gb = (G + 255) / 256;

  k_hist1 <<<NBLK1, 512, 0, stream>>>(col, hist1, E, C, chunk1);
  k_cscan1<<<C, NBLK1, 0, stream>>>(hist1, hofs1, totals1, C);
  k_bscan1<<<1, 64, 0, stream>>>(totals1, bstart1, rowptr, C, N, E);
  k_part1 <<<NBLK1, 512, 0, stream>>>(row, col, ew, bstart1, hofs1, recs1, E, C, chunk1);
  k_hist2 <<<C * K2, 1024, 0, stream>>>(recs1, bstart1, cnt2);
  k_cscan2<<<C, 512, 0, stream>>>(cnt2, bstart1, hofs2, bstart2, C, E);
  k_part2 <<<C * K2, 1024, 0, stream>>>(recs1, bstart1, hofs2, bstart2, recs2);
  k_build <<<NBF, 256, 0, stream>>>(recs2, bstart2, rowptr, csr, dinv, N);
  k_gemm1 <<<nb, 256, 0, stream>>>(x, W1, dinv, ht1, N);
  k_agg1  <<<ab, 256, 0, stream>>>(ht1, rowptr, csr, dinv, b1, W2, ht2, N);
  k_agg2  <<<ab, 256, 0, stream>>>(ht2, rowptr, csr, dinv, b2, batch, pooled, N);
  k_final <<<gb, 256, 0, stream>>>(pooled, batch, fcW, fcb, out, N, G);
}

// Round 13
// 166.372 us; speedup vs baseline: 1.4054x; 1.0072x over previous
//
#include <hip/hip_runtime.h>
#include <hip/hip_fp16.h>

typedef unsigned int u32;
typedef unsigned char u8;

static inline size_t al16(size_t x){ return (x + 15) & ~(size_t)15; }

#define CSH 12             // 4096 nodes per coarse bucket
#define NBLK1 512          // level-1 partition blocks (512 thr): run = E/(512*25) ~250 edges
#define K2 16              // level-2 chunks per coarse region
#define FPB 32             // fine buckets per coarse (4096/128)
#define NPB 128            // nodes per fine bucket
#define PBSH 7
#define SRCMSK 0xFFFFFu
#define STAGE_CAP 5120     // LDS staging (edges) per fine bucket; avg ~4000, std ~63 -> never overflows

// L1 hist: per-block LDS histogram of coarse buckets. hist1 layout [blk][C].
// Block 0 additionally zeroes `pooled` (replaces a graph-captured hipMemsetAsync
// node that cost ~40us/replay).
__global__ void k_hist1(const int* __restrict__ col, u32* __restrict__ hist1,
                        float* __restrict__ pooled, int PG, int E, int C, int chunk) {
  __shared__ u32 h[64];
  int tid = threadIdx.x, blk = blockIdx.x;
  if (blk == 0) for (int i = tid; i < PG; i += 512) pooled[i] = 0.f;
  if (tid < 64) h[tid] = 0;
  __syncthreads();
  int e0 = blk * chunk, e1 = min(E, e0 + chunk);
  for (int e = e0 + tid; e < e1; e += 512) atomicAdd(&h[col[e] >> CSH], 1u);
  __syncthreads();
  if (tid < C) hist1[(size_t)blk * C + tid] = h[tid];
}

// L1 scan: per coarse bucket, exclusive scan over NBLK1 blocks.
__global__ void k_cscan1(const u32* __restrict__ hist1, u32* __restrict__ hofs1,
                         u32* __restrict__ totals1, int C) {
  __shared__ u32 s[NBLK1];
  int i = blockIdx.x, t = threadIdx.x;
  u32 v = hist1[(size_t)t * C + i];
  s[t] = v; __syncthreads();
  for (int off = 1; off < NBLK1; off <<= 1) {
    u32 x = (t >= off) ? s[t - off] : 0u;
    __syncthreads(); s[t] += x; __syncthreads();
  }
  hofs1[(size_t)i * NBLK1 + t] = s[t] - v;
  if (t == NBLK1 - 1) totals1[i] = s[t];
}

// L1 bucket-total scan (C<=64, trivial serial) + sentinels.
__global__ void k_bscan1(const u32* __restrict__ totals1, u32* __restrict__ bstart1,
                         u32* __restrict__ rowptr, int C, int N, int E) {
  if (threadIdx.x == 0) {
    u32 a = 0;
    for (int i = 0; i < C; i++) { bstart1[i] = a; a += totals1[i]; }
    bstart1[C] = (u32)E;
    rowptr[N] = (u32)E;
  }
}

// L1 scatter: {src | dl12<<20, w} into coarse-contiguous recs1 + 1B fine-bucket
// id stream (lets k_hist2 read 3.2MB instead of 25.6MB). LDS cursors.
__global__ void k_part1(const int* __restrict__ row, const int* __restrict__ col,
                        const float* __restrict__ ew, const u32* __restrict__ bstart1,
                        const u32* __restrict__ hofs1, uint2* __restrict__ recs1,
                        u8* __restrict__ fid, int E, int C, int chunk) {
  __shared__ u32 cur[64];
  int tid = threadIdx.x, blk = blockIdx.x;
  if (tid < C) cur[tid] = bstart1[tid] + hofs1[(size_t)tid * NBLK1 + blk];
  __syncthreads();
  int e0 = blk * chunk, e1 = min(E, e0 + chunk);
  for (int e = e0 + tid; e < e1; e += 512) {
    int c = col[e];
    int cb = c >> CSH;
    u32 dl12 = (u32)(c & 4095);
    u32 pos = atomicAdd(&cur[cb], 1u);
    uint2 v; v.x = (u32)row[e] | (dl12 << 20); v.y = __float_as_uint(ew[e]);
    recs1[pos] = v;
    fid[pos] = (u8)(dl12 >> PBSH);
  }
}

// L2 hist: block (cb,k) = chunk k of coarse region cb; 32 fine-bucket counters.
__global__ void k_hist2(const u8* __restrict__ fid, const u32* __restrict__ bstart1,
                        u32* __restrict__ cnt2) {
  __shared__ u32 h[FPB];
  int cb = blockIdx.x >> 4, k = blockIdx.x & 15;
  int t = threadIdx.x;
  if (t < FPB) h[t] = 0;
  __syncthreads();
  u32 r0 = bstart1[cb], r1 = bstart1[cb + 1];
  u32 len = r1 - r0, ch = (len + K2 - 1) / K2;
  u32 e0 = r0 + (u32)k * ch, e1 = min(r1, e0 + ch);
  for (u32 e = e0 + t; e < e1; e += 1024) atomicAdd(&h[fid[e]], 1u);
  __syncthreads();
  if (t < FPB) cnt2[((size_t)cb * K2 + k) * FPB + t] = h[t];
}

// L2 scan: per coarse bucket, scan (fine-major, chunk-minor) 512 values ->
// hofs2[cb][f][k], bstart2[cb*32+f].
__global__ void k_cscan2(const u32* __restrict__ cnt2, const u32* __restrict__ bstart1,
                         u32* __restrict__ hofs2, u32* __restrict__ bstart2,
                         int C, int E) {
  __shared__ u32 s[512];
  __shared__ u32 sx[512];
  int cb = blockIdx.x, t = threadIdx.x;
  int f = t >> 4, k = t & 15;
  u32 v = cnt2[((size_t)cb * K2 + k) * FPB + f];
  s[t] = v; __syncthreads();
  for (int off = 1; off < 512; off <<= 1) {
    u32 x = (t >= off) ? s[t - off] : 0u;
    __syncthreads(); s[t] += x; __syncthreads();
  }
  sx[t] = s[t] - v;
  __syncthreads();
  hofs2[((size_t)cb * FPB + f) * K2 + k] = sx[t] - sx[f << 4];
  if (k == 0) bstart2[cb * FPB + f] = bstart1[cb] + sx[t];
  if (cb == C - 1 && t == 0) bstart2[C * FPB] = (u32)E;
}

// L2 scatter: fine-bucket-contiguous recs2. 32 LDS cursors.
__global__ void k_part2(const uint2* __restrict__ recs1, const u32* __restrict__ bstart1,
                        const u32* __restrict__ hofs2, const u32* __restrict__ bstart2,
                        uint2* __restrict__ recs2) {
  __shared__ u32 cur[FPB];
  int cb = blockIdx.x >> 4, k = blockIdx.x & 15;
  int t = threadIdx.x;
  if (t < FPB) cur[t] = bstart2[cb * FPB + t] + hofs2[((size_t)cb * FPB + t) * K2 + k];
  __syncthreads();
  u32 r0 = bstart1[cb], r1 = bstart1[cb + 1];
  u32 len = r1 - r0, ch = (len + K2 - 1) / K2;
  u32 e0 = r0 + (u32)k * ch, e1 = min(r1, e0 + ch);
  for (u32 e = e0 + t; e < e1; e += 1024) {
    uint2 v = recs1[e];
    u32 pos = atomicAdd(&cur[v.x >> 27], 1u);
    recs2[pos] = v;
  }
}

// Build: one block per fine bucket. count -> scan -> LDS-staged sort ->
// coalesced csr write-out + rowptr + FUSED weighted-degree -> dinv.
__global__ void k_build(const uint2* __restrict__ recs2, const u32* __restrict__ bstart2,
                        u32* __restrict__ rowptr, uint2* __restrict__ csr,
                        float* __restrict__ dinv, int N) {
  __shared__ uint2 stage[STAGE_CAP];
  __shared__ u32 cnt[NPB];
  __shared__ u32 sc[NPB];
  __shared__ u32 cur[NPB];
  int b = blockIdx.x, t = threadIdx.x;
  if (t < NPB) cnt[t] = 0;
  __syncthreads();
  u32 r0 = bstart2[b], r1 = bstart2[b + 1];
  int cap_ok = (r1 - r0) <= STAGE_CAP;
  for (u32 e = r0 + t; e < r1; e += 256) atomicAdd(&cnt[(recs2[e].x >> 20) & 127], 1u);
  __syncthreads();
  if (t < NPB) sc[t] = cnt[t];
  __syncthreads();
  for (int off = 1; off < NPB; off <<= 1) {
    u32 x = (t < NPB && t >= off) ? sc[t - off] : 0u;
    __syncthreads();
    if (t < NPB) sc[t] += x;
    __syncthreads();
  }
  if (t < NPB) {
    u32 excl = sc[t] - cnt[t];
    int node = (b << PBSH) + t;
    if (node < N) rowptr[node] = r0 + excl;
    cur[t] = excl;
  }
  __syncthreads();
  if (cap_ok) {
    for (u32 e = r0 + t; e < r1; e += 256) {
      uint2 v = recs2[e];
      u32 dl = (v.x >> 20) & 127;
      u32 slot = atomicAdd(&cur[dl], 1u);
      uint2 o; o.x = v.x & SRCMSK; o.y = v.y;
      stage[slot] = o;
    }
    __syncthreads();
    for (u32 i = t; i < r1 - r0; i += 256) csr[r0 + i] = stage[i];
    if (t < NPB) {
      int node = (b << PBSH) + t;
      if (node < N) {
        u32 base = sc[t] - cnt[t], c = cnt[t];
        float sd = 0.f;
        for (u32 i = 0; i < c; i++) sd += __uint_as_float(stage[base + i].y);
        dinv[node] = rsqrtf(sd + 1.0f);   // +1 = self-loop weight
      }
    }
  } else {
    for (u32 e = r0 + t; e < r1; e += 256) {
      uint2 v = recs2[e];
      u32 dl = (v.x >> 20) & 127;
      u32 slot = atomicAdd(&cur[dl], 1u);
      uint2 o; o.x = v.x & SRCMSK; o.y = v.y;
      csr[r0 + slot] = o;
    }
    __syncthreads();
    if (t < NPB) {
      int node = (b << PBSH) + t;
      if (node < N) {
        u32 base = r0 + sc[t] - cnt[t], c = cnt[t];
        float sd = 0.f;
        for (u32 i = 0; i < c; i++) sd += __uint_as_float(csr[base + i].y);
        dinv[node] = rsqrtf(sd + 1.0f);
      }
    }
  }
}

// ht1' = dinv[node] * (x @ W1), fp16 node-major (dinv folded; runs AFTER build).
__global__ void k_gemm1(const float* __restrict__ x, const float* __restrict__ W1,
                        const float* __restrict__ dinv, __half* __restrict__ ht1, int n) {
  __shared__ float sw[2048];
  for (int i = threadIdx.x; i < 2048; i += blockDim.x) sw[i] = W1[i];
  __syncthreads();
  int node = blockIdx.x * blockDim.x + threadIdx.x;
  if (node >= n) return;
  const float4* xr = (const float4*)(x + (size_t)node * 128);
  float acc[16];
  #pragma unroll
  for (int j = 0; j < 16; j++) acc[j] = 0.f;
  #pragma unroll 4
  for (int k4 = 0; k4 < 32; k4++) {
    float4 xv = xr[k4];
    const float* wb = &sw[k4 * 64];
    #pragma unroll
    for (int j = 0; j < 16; j++) acc[j] += xv.x * wb[j];
    #pragma unroll
    for (int j = 0; j < 16; j++) acc[j] += xv.y * wb[16 + j];
    #pragma unroll
    for (int j = 0; j < 16; j++) acc[j] += xv.z * wb[32 + j];
    #pragma unroll
    for (int j = 0; j < 16; j++) acc[j] += xv.w * wb[48 + j];
  }
  float di = dinv[node];
  u32 o[8];
  #pragma unroll
  for (int p = 0; p < 8; p++) {
    u32 lo = (u32)__half_as_ushort(__float2half(di * acc[2 * p]));
    u32 hi = (u32)__half_as_ushort(__float2half(di * acc[2 * p + 1]));
    o[p] = lo | (hi << 16);
  }
  uint4* dst = (uint4*)(ht1 + (size_t)node * 16);
  dst[0] = make_uint4(o[0], o[1], o[2], o[3]);
  dst[1] = make_uint4(o[4], o[5], o[6], o[7]);
}

// Per-edge core, 8 lanes/node: lane s owns channels {2s,2s+1}. Per 8-edge batch,
// lane s loads csr[e+s] (coalesced) and {src,w} are distributed via width-8
// shuffles; each lane gathers its 4B of the 32B ht row. Tail padded with w=0.
__device__ __forceinline__ void edge_sum2(const __half* __restrict__ ht,
                                          const uint2* __restrict__ csr,
                                          u32 e0, u32 e1, int s,
                                          float& a0, float& a1) {
  for (u32 e = e0; e < e1; e += 8) {
    u32 idx = e + (u32)s;
    uint2 r = (idx < e1) ? csr[idx] : make_uint2(0u, 0u);
    #pragma unroll
    for (int t = 0; t < 8; t++) {
      u32 srct = (u32)__shfl((int)r.x, t, 8);
      float wt = __uint_as_float((u32)__shfl((int)r.y, t, 8));
      u32 hw = *(const u32*)((const char*)ht + (size_t)srct * 32 + s * 4);
      float2 hf = __half22float2(*(__half2*)&hw);
      a0 += wt * hf.x;
      a1 += wt * hf.y;
    }
  }
}

// Conv1 agg + bias + relu, fused @W2; epilogue scales by dinv for agg2's table.
// 8 lanes/node, 32 nodes per 256-thread block.
__global__ void k_agg1(const __half* __restrict__ ht1, const u32* __restrict__ rowptr,
                       const uint2* __restrict__ csr, const float* __restrict__ dinv,
                       const float* __restrict__ b1, const float* __restrict__ W2,
                       __half* __restrict__ ht2, int n) {
  __shared__ float sw2[256];
  __shared__ float sr[32][18];
  int tid = threadIdx.x;
  sw2[tid] = W2[tid];
  int g = tid >> 3, s = tid & 7;
  int node = blockIdx.x * 32 + g;
  float a0 = 0.f, a1 = 0.f, di = 0.f;
  if (node < n) {
    u32 e0 = rowptr[node], e1 = rowptr[node + 1];
    edge_sum2(ht1, csr, e0, e1, s, a0, a1);
    di = dinv[node];
    u32 hs = *(const u32*)((const char*)ht1 + (size_t)node * 32 + s * 4);
    float2 sf = __half22float2(*(__half2*)&hs);
    a0 = fmaxf(di * (a0 + sf.x) + b1[2 * s + 0], 0.f);
    a1 = fmaxf(di * (a1 + sf.y) + b1[2 * s + 1], 0.f);
  }
  sr[g][2 * s] = a0; sr[g][2 * s + 1] = a1;
  __syncthreads();
  if (node < n) {
    float o0 = 0.f, o1 = 0.f;
    #pragma unroll
    for (int k = 0; k < 16; k++) {
      float hk = sr[g][k];
      o0 += hk * sw2[k * 16 + 2 * s];
      o1 += hk * sw2[k * 16 + 2 * s + 1];
    }
    __half2 p = __floats2half2_rn(di * o0, di * o1);
    *(u32*)((char*)ht2 + (size_t)node * 32 + s * 4) = *(u32*)&p;
  }
}

// Conv2 agg + bias, fused mean-pool partials (segmented LDS reduce + native f32 atomics).
__global__ void k_agg2(const __half* __restrict__ ht2, const u32* __restrict__ rowptr,
                       const uint2* __restrict__ csr, const float* __restrict__ dinv,
                       const float* __restrict__ b2, const int* __restrict__ batch,
                       float* __restrict__ pooled, int n) {
  __shared__ float sr[32][18];
  __shared__ int sbid[32];
  int tid = threadIdx.x;
  int g = tid >> 3, s = tid & 7;
  int node = blockIdx.x * 32 + g;
  float a0 = 0.f, a1 = 0.f;
  int myb = -1;
  if (node < n) {
    u32 e0 = rowptr[node], e1 = rowptr[node + 1];
    edge_sum2(ht2, csr, e0, e1, s, a0, a1);
    float di = dinv[node];
    u32 hs = *(const u32*)((const char*)ht2 + (size_t)node * 32 + s * 4);
    float2 sf = __half22float2(*(__half2*)&hs);
    a0 = di * (a0 + sf.x) + b2[2 * s + 0];
    a1 = di * (a1 + sf.y) + b2[2 * s + 1];
    myb = batch[node];
  }
  sr[g][2 * s] = a0; sr[g][2 * s + 1] = a1;
  if (s == 0) sbid[g] = myb;
  __syncthreads();
  if (node < n) {
    bool head = (g == 0) || (sbid[g - 1] != myb);
    if (head) {
      float s0 = a0, s1 = a1;
      for (int t = g + 1; t < 32 && sbid[t] == myb; t++) {
        s0 += sr[t][2 * s]; s1 += sr[t][2 * s + 1];
      }
      float* pb = &pooled[(size_t)myb * 16 + 2 * s];
      unsafeAtomicAdd(pb + 0, s0);
      unsafeAtomicAdd(pb + 1, s1);
    }
  }
}

// Mean + FC. Graph sizes via binary search on sorted batch.
__global__ void k_final(const float* __restrict__ pooled, const int* __restrict__ batch,
                        const float* __restrict__ fcW, const float* __restrict__ fcb,
                        float* __restrict__ out, int n, int G) {
  int g = blockIdx.x * blockDim.x + threadIdx.x;
  if (g >= G) return;
  int lo = 0, hi = n;
  while (lo < hi) { int m = (lo + hi) >> 1; if (batch[m] < g) lo = m + 1; else hi = m; }
  int lo2 = lo, hi2 = n;
  while (lo2 < hi2) { int m = (lo2 + hi2) >> 1; if (batch[m] < g + 1) lo2 = m + 1; else hi2 = m; }
  float c = (float)(lo2 - lo);
  float inv = 1.0f / fmaxf(c, 1.0f);
  float s = 0.f;
  #pragma unroll
  for (int j = 0; j < 16; j++) s += pooled[g * 16 + j] * fcW[j];
  out[g] = s * inv + fcb[0];
}

extern "C" void kernel_launch(void* const* d_in, const int* in_sizes, int n_in,
                              void* d_out, int out_size, void* d_ws, size_t ws_size,
                              hipStream_t stream) {
  const float* x    = (const float*)d_in[0];
  const int*   ei   = (const int*)d_in[1];
  const float* ew   = (const float*)d_in[2];
  const int*   batch= (const int*)d_in[3];
  const float* W1   = (const float*)d_in[4];
  const float* b1   = (const float*)d_in[5];
  const float* W2   = (const float*)d_in[6];
  const float* b2   = (const float*)d_in[7];
  const float* fcW  = (const float*)d_in[8];
  const float* fcb  = (const float*)d_in[9];
  float* out = (float*)d_out;

  int N = in_sizes[3];
  int E = in_sizes[2];
  int G = out_size;
  const int* row = ei;     // edge_index[0] = source
  const int* col = ei + E; // edge_index[1] = target

  int C   = (N + 4095) >> CSH;   // 25 coarse buckets
  int NBF = C * FPB;             // 800 fine buckets
  int chunk1 = (E + NBLK1 - 1) / NBLK1;

  char* w = (char*)d_ws;
  size_t off = 0;
  auto alloc = [&](size_t bytes) -> char* { char* p = w + off; off = al16(off + bytes); return p; };
  u32*   hist1   = (u32*)  alloc((size_t)NBLK1 * C * 4);
  u32*   hofs1   = (u32*)  alloc((size_t)C * NBLK1 * 4);
  u32*   totals1 = (u32*)  alloc((size_t)C * 4);
  u32*   bstart1 = (u32*)  alloc(((size_t)C + 1) * 4);
  u32*   cnt2    = (u32*)  alloc((size_t)C * K2 * FPB * 4);
  u32*   hofs2   = (u32*)  alloc((size_t)C * FPB * K2 * 4);
  u32*   bstart2 = (u32*)  alloc(((size_t)NBF + 1) * 4);
  u32*   rowptr  = (u32*)  alloc(((size_t)N + 1) * 4);
  float* dinv    = (float*)alloc((size_t)N * 4);
  u8*    fid     = (u8*)   alloc((size_t)E);
  uint2* recs1   = (uint2*)alloc((size_t)E * 8);
  uint2* recs2   = (uint2*)alloc((size_t)E * 8);
  float* pooled  = (float*)alloc((size_t)G * 16 * 4);
  // Aliases: csr overlays recs1 (dead after part2); ht1/ht2 overlay recs2 (dead after build).
  uint2*  csr = recs1;
  __half* ht1 = (__half*)recs2;
  __half* ht2 = (__half*)((char*)recs2 + (size_t)N * 16 * 2);
  (void)n_in; (void)ws_size;

  int nb = (N + 255) / 256;
  int ab = (N + 31) / 32;
  int gb = (G + 255) / 256;

  k_hist1 <<<NBLK1, 512, 0, stream>>>(col, hist1, pooled, G * 16, E, C, chunk1);
  k_cscan1<<<C, NBLK1, 0, stream>>>(hist1, hofs1, totals1, C);
  k_bscan1<<<1, 64, 0, stream>>>(totals1, bstart1, rowptr, C, N, E);
  k_part1 <<<NBLK1, 512, 0, stream>>>(row, col, ew, bstart1, hofs1, recs1, fid, E, C, chunk1);
  k_hist2 <<<C * K2, 1024, 0, stream>>>(fid, bstart1, cnt2);
  k_cscan2<<<C, 512, 0, stream>>>(cnt2, bstart1, hofs2, bstart2, C, E);
  k_part2 <<<C * K2, 1024, 0, stream>>>(recs1, bstart1, hofs2, bstart2, recs2);
  k_build <<<NBF, 256, 0, stream>>>(recs2, bstart2, rowptr, csr, dinv, N);
  k_gemm1 <<<nb, 256, 0, stream>>>(x, W1, dinv, ht1, N);
  k_agg1  <<<ab, 256, 0, stream>>>(ht1, rowptr, csr, dinv, b1, W2, ht2, N);
  k_agg2  <<<ab, 256, 0, stream>>>(ht2, rowptr, csr, dinv, b2, batch, pooled, N);
  k_final <<<gb, 256, 0, stream>>>(pooled, batch, fcW, fcb, out, N, G);
}

// Round 14
// 162.011 us; speedup vs baseline: 1.4433x; 1.0269x over previous
//
#include <hip/hip_runtime.h>
#include <hip/hip_fp16.h>

typedef unsigned int u32;
typedef unsigned char u8;

static inline size_t al16(size_t x){ return (x + 15) & ~(size_t)15; }

#define CSH 12             // 4096 nodes per coarse bucket
#define NBLK1 512          // level-1 partition blocks (512 thr): run = E/(512*25) ~250 edges
#define K2 16              // level-2 chunks per coarse region
#define FPB 32             // fine buckets per coarse (4096/128)
#define NPB 128            // nodes per fine bucket
#define PBSH 7
#define SRCMSK 0xFFFFFu
#define STAGE_CAP 5120     // LDS staging (edges) per fine bucket; avg ~4000, std ~63 -> never overflows

// L1 hist: per-block LDS histogram of coarse buckets, 2 edges/thread vectorized.
// Block 0 also zeroes pooled and sets rowptr[N] sentinel.
__global__ void k_hist1(const int* __restrict__ col, u32* __restrict__ hist1,
                        float* __restrict__ pooled, u32* __restrict__ rowptr,
                        int PG, int N, int E, int C, int chunk) {
  __shared__ u32 h[64];
  int tid = threadIdx.x, blk = blockIdx.x;
  if (blk == 0) {
    for (int i = tid; i < PG; i += 512) pooled[i] = 0.f;
    if (tid == 0) rowptr[N] = (u32)E;
  }
  if (tid < 64) h[tid] = 0;
  __syncthreads();
  int e0 = blk * chunk, e1 = min(E, e0 + chunk);
  for (int e = e0 + 2 * tid; e < e1; e += 1024) {
    if (e + 1 < e1) {
      int2 cc = *(const int2*)(col + e);
      atomicAdd(&h[cc.x >> CSH], 1u);
      atomicAdd(&h[cc.y >> CSH], 1u);
    } else {
      atomicAdd(&h[col[e] >> CSH], 1u);
    }
  }
  __syncthreads();
  if (tid < C) hist1[(size_t)blk * C + tid] = h[tid];
}

// L1 scan: per coarse bucket, exclusive scan over NBLK1 blocks.
__global__ void k_cscan1(const u32* __restrict__ hist1, u32* __restrict__ hofs1,
                         u32* __restrict__ totals1, int C) {
  __shared__ u32 s[NBLK1];
  int i = blockIdx.x, t = threadIdx.x;
  u32 v = hist1[(size_t)t * C + i];
  s[t] = v; __syncthreads();
  for (int off = 1; off < NBLK1; off <<= 1) {
    u32 x = (t >= off) ? s[t - off] : 0u;
    __syncthreads(); s[t] += x; __syncthreads();
  }
  hofs1[(size_t)i * NBLK1 + t] = s[t] - v;
  if (t == NBLK1 - 1) totals1[i] = s[t];
}

// L1 scatter, 2 edges/thread vectorized. Bucket bases computed in-block from
// totals1 (25 serial adds); block 0 materializes bstart1 for later kernels.
__global__ void k_part1(const int* __restrict__ row, const int* __restrict__ col,
                        const float* __restrict__ ew, const u32* __restrict__ totals1,
                        u32* __restrict__ bstart1, const u32* __restrict__ hofs1,
                        uint2* __restrict__ recs1, u8* __restrict__ fid,
                        int E, int C, int chunk) {
  __shared__ u32 cur[64];
  __shared__ u32 bs[64];
  int tid = threadIdx.x, blk = blockIdx.x;
  if (tid == 0) {
    u32 a = 0;
    for (int i = 0; i < C; i++) { bs[i] = a; a += totals1[i]; }
    if (blk == 0) {
      for (int i = 0; i < C; i++) bstart1[i] = bs[i];
      bstart1[C] = (u32)E;
    }
  }
  __syncthreads();
  if (tid < C) cur[tid] = bs[tid] + hofs1[(size_t)tid * NBLK1 + blk];
  __syncthreads();
  int e0 = blk * chunk, e1 = min(E, e0 + chunk);
  for (int e = e0 + 2 * tid; e < e1; e += 1024) {
    int2 rr, cc; float2 wv;
    bool two = (e + 1 < e1);
    if (two) {
      rr = *(const int2*)(row + e);
      cc = *(const int2*)(col + e);
      wv = *(const float2*)(ew + e);
    } else {
      rr.x = row[e]; cc.x = col[e]; wv.x = ew[e];
      rr.y = 0; cc.y = 0; wv.y = 0.f;
    }
    {
      int c = cc.x, cb = c >> CSH;
      u32 dl12 = (u32)(c & 4095);
      u32 pos = atomicAdd(&cur[cb], 1u);
      uint2 v; v.x = (u32)rr.x | (dl12 << 20); v.y = __float_as_uint(wv.x);
      recs1[pos] = v;
      fid[pos] = (u8)(dl12 >> PBSH);
    }
    if (two) {
      int c = cc.y, cb = c >> CSH;
      u32 dl12 = (u32)(c & 4095);
      u32 pos = atomicAdd(&cur[cb], 1u);
      uint2 v; v.x = (u32)rr.y | (dl12 << 20); v.y = __float_as_uint(wv.y);
      recs1[pos] = v;
      fid[pos] = (u8)(dl12 >> PBSH);
    }
  }
}

// L2 hist: block (cb,k) = chunk k of coarse region cb; 32 fine-bucket counters.
__global__ void k_hist2(const u8* __restrict__ fid, const u32* __restrict__ bstart1,
                        u32* __restrict__ cnt2) {
  __shared__ u32 h[FPB];
  int cb = blockIdx.x >> 4, k = blockIdx.x & 15;
  int t = threadIdx.x;
  if (t < FPB) h[t] = 0;
  __syncthreads();
  u32 r0 = bstart1[cb], r1 = bstart1[cb + 1];
  u32 len = r1 - r0, ch = (len + K2 - 1) / K2;
  u32 e0 = r0 + (u32)k * ch, e1 = min(r1, e0 + ch);
  for (u32 e = e0 + t; e < e1; e += 1024) atomicAdd(&h[fid[e]], 1u);
  __syncthreads();
  if (t < FPB) cnt2[((size_t)cb * K2 + k) * FPB + t] = h[t];
}

// L2 scan: per coarse bucket, scan (fine-major, chunk-minor) 512 values ->
// hofs2[cb][f][k], bstart2[cb*32+f].
__global__ void k_cscan2(const u32* __restrict__ cnt2, const u32* __restrict__ bstart1,
                         u32* __restrict__ hofs2, u32* __restrict__ bstart2,
                         int C, int E) {
  __shared__ u32 s[512];
  __shared__ u32 sx[512];
  int cb = blockIdx.x, t = threadIdx.x;
  int f = t >> 4, k = t & 15;
  u32 v = cnt2[((size_t)cb * K2 + k) * FPB + f];
  s[t] = v; __syncthreads();
  for (int off = 1; off < 512; off <<= 1) {
    u32 x = (t >= off) ? s[t - off] : 0u;
    __syncthreads(); s[t] += x; __syncthreads();
  }
  sx[t] = s[t] - v;
  __syncthreads();
  hofs2[((size_t)cb * FPB + f) * K2 + k] = sx[t] - sx[f << 4];
  if (k == 0) bstart2[cb * FPB + f] = bstart1[cb] + sx[t];
  if (cb == C - 1 && t == 0) bstart2[C * FPB] = (u32)E;
}

// L2 scatter: fine-bucket-contiguous recs2. 32 LDS cursors.
__global__ void k_part2(const uint2* __restrict__ recs1, const u32* __restrict__ bstart1,
                        const u32* __restrict__ hofs2, const u32* __restrict__ bstart2,
                        uint2* __restrict__ recs2) {
  __shared__ u32 cur[FPB];
  int cb = blockIdx.x >> 4, k = blockIdx.x & 15;
  int t = threadIdx.x;
  if (t < FPB) cur[t] = bstart2[cb * FPB + t] + hofs2[((size_t)cb * FPB + t) * K2 + k];
  __syncthreads();
  u32 r0 = bstart1[cb], r1 = bstart1[cb + 1];
  u32 len = r1 - r0, ch = (len + K2 - 1) / K2;
  u32 e0 = r0 + (u32)k * ch, e1 = min(r1, e0 + ch);
  for (u32 e = e0 + t; e < e1; e += 1024) {
    uint2 v = recs1[e];
    u32 pos = atomicAdd(&cur[v.x >> 27], 1u);
    recs2[pos] = v;
  }
}

// Build: one block per fine bucket. count -> scan -> LDS-staged sort ->
// coalesced csr write-out + rowptr + FUSED weighted-degree -> dinv.
__global__ void k_build(const uint2* __restrict__ recs2, const u32* __restrict__ bstart2,
                        u32* __restrict__ rowptr, uint2* __restrict__ csr,
                        float* __restrict__ dinv, int N) {
  __shared__ uint2 stage[STAGE_CAP];
  __shared__ u32 cnt[NPB];
  __shared__ u32 sc[NPB];
  __shared__ u32 cur[NPB];
  int b = blockIdx.x, t = threadIdx.x;
  if (t < NPB) cnt[t] = 0;
  __syncthreads();
  u32 r0 = bstart2[b], r1 = bstart2[b + 1];
  int cap_ok = (r1 - r0) <= STAGE_CAP;
  for (u32 e = r0 + t; e < r1; e += 256) atomicAdd(&cnt[(recs2[e].x >> 20) & 127], 1u);
  __syncthreads();
  if (t < NPB) sc[t] = cnt[t];
  __syncthreads();
  for (int off = 1; off < NPB; off <<= 1) {
    u32 x = (t < NPB && t >= off) ? sc[t - off] : 0u;
    __syncthreads();
    if (t < NPB) sc[t] += x;
    __syncthreads();
  }
  if (t < NPB) {
    u32 excl = sc[t] - cnt[t];
    int node = (b << PBSH) + t;
    if (node < N) rowptr[node] = r0 + excl;
    cur[t] = excl;
  }
  __syncthreads();
  if (cap_ok) {
    for (u32 e = r0 + t; e < r1; e += 256) {
      uint2 v = recs2[e];
      u32 dl = (v.x >> 20) & 127;
      u32 slot = atomicAdd(&cur[dl], 1u);
      uint2 o; o.x = v.x & SRCMSK; o.y = v.y;
      stage[slot] = o;
    }
    __syncthreads();
    for (u32 i = t; i < r1 - r0; i += 256) csr[r0 + i] = stage[i];
    if (t < NPB) {
      int node = (b << PBSH) + t;
      if (node < N) {
        u32 base = sc[t] - cnt[t], c = cnt[t];
        float sd = 0.f;
        for (u32 i = 0; i < c; i++) sd += __uint_as_float(stage[base + i].y);
        dinv[node] = rsqrtf(sd + 1.0f);   // +1 = self-loop weight
      }
    }
  } else {
    for (u32 e = r0 + t; e < r1; e += 256) {
      uint2 v = recs2[e];
      u32 dl = (v.x >> 20) & 127;
      u32 slot = atomicAdd(&cur[dl], 1u);
      uint2 o; o.x = v.x & SRCMSK; o.y = v.y;
      csr[r0 + slot] = o;
    }
    __syncthreads();
    if (t < NPB) {
      int node = (b << PBSH) + t;
      if (node < N) {
        u32 base = r0 + sc[t] - cnt[t], c = cnt[t];
        float sd = 0.f;
        for (u32 i = 0; i < c; i++) sd += __uint_as_float(csr[base + i].y);
        dinv[node] = rsqrtf(sd + 1.0f);
      }
    }
  }
}

// ht1' = dinv[node] * (x @ W1), fp16 node-major (dinv folded; runs AFTER build).
__global__ void k_gemm1(const float* __restrict__ x, const float* __restrict__ W1,
                        const float* __restrict__ dinv, __half* __restrict__ ht1, int n) {
  __shared__ float sw[2048];
  for (int i = threadIdx.x; i < 2048; i += blockDim.x) sw[i] = W1[i];
  __syncthreads();
  int node = blockIdx.x * blockDim.x + threadIdx.x;
  if (node >= n) return;
  const float4* xr = (const float4*)(x + (size_t)node * 128);
  float acc[16];
  #pragma unroll
  for (int j = 0; j < 16; j++) acc[j] = 0.f;
  #pragma unroll 4
  for (int k4 = 0; k4 < 32; k4++) {
    float4 xv = xr[k4];
    const float* wb = &sw[k4 * 64];
    #pragma unroll
    for (int j = 0; j < 16; j++) acc[j] += xv.x * wb[j];
    #pragma unroll
    for (int j = 0; j < 16; j++) acc[j] += xv.y * wb[16 + j];
    #pragma unroll
    for (int j = 0; j < 16; j++) acc[j] += xv.z * wb[32 + j];
    #pragma unroll
    for (int j = 0; j < 16; j++) acc[j] += xv.w * wb[48 + j];
  }
  float di = dinv[node];
  u32 o[8];
  #pragma unroll
  for (int p = 0; p < 8; p++) {
    u32 lo = (u32)__half_as_ushort(__float2half(di * acc[2 * p]));
    u32 hi = (u32)__half_as_ushort(__float2half(di * acc[2 * p + 1]));
    o[p] = lo | (hi << 16);
  }
  uint4* dst = (uint4*)(ht1 + (size_t)node * 16);
  dst[0] = make_uint4(o[0], o[1], o[2], o[3]);
  dst[1] = make_uint4(o[4], o[5], o[6], o[7]);
}

// Per-edge core, 8 lanes/node: 16-edge double batches with two independent csr
// loads and split accumulators (ILP); 8-edge masked remainder.
__device__ __forceinline__ void edge_sum2(const __half* __restrict__ ht,
                                          const uint2* __restrict__ csr,
                                          u32 e0, u32 e1, int s,
                                          float& a0, float& a1) {
  float b0 = 0.f, b1 = 0.f;
  u32 e = e0;
  for (; e + 16 <= e1; e += 16) {
    uint2 rA = csr[e + (u32)s];
    uint2 rB = csr[e + 8 + (u32)s];
    #pragma unroll
    for (int t = 0; t < 8; t++) {
      u32 sA = (u32)__shfl((int)rA.x, t, 8);
      float wA = __uint_as_float((u32)__shfl((int)rA.y, t, 8));
      u32 sB = (u32)__shfl((int)rB.x, t, 8);
      float wB = __uint_as_float((u32)__shfl((int)rB.y, t, 8));
      u32 hA = *(const u32*)((const char*)ht + (size_t)sA * 32 + s * 4);
      u32 hB = *(const u32*)((const char*)ht + (size_t)sB * 32 + s * 4);
      float2 fA = __half22float2(*(__half2*)&hA);
      float2 fB = __half22float2(*(__half2*)&hB);
      a0 += wA * fA.x; a1 += wA * fA.y;
      b0 += wB * fB.x; b1 += wB * fB.y;
    }
  }
  for (; e < e1; e += 8) {
    u32 idx = e + (u32)s;
    uint2 r = (idx < e1) ? csr[idx] : make_uint2(0u, 0u);
    #pragma unroll
    for (int t = 0; t < 8; t++) {
      u32 srct = (u32)__shfl((int)r.x, t, 8);
      float wt = __uint_as_float((u32)__shfl((int)r.y, t, 8));
      u32 hw = *(const u32*)((const char*)ht + (size_t)srct * 32 + s * 4);
      float2 hf = __half22float2(*(__half2*)&hw);
      a0 += wt * hf.x;
      a1 += wt * hf.y;
    }
  }
  a0 += b0; a1 += b1;
}

// Conv1 agg + bias + relu, fused @W2; epilogue scales by dinv for agg2's table.
// 8 lanes/node, 32 nodes per 256-thread block.
__global__ void k_agg1(const __half* __restrict__ ht1, const u32* __restrict__ rowptr,
                       const uint2* __restrict__ csr, const float* __restrict__ dinv,
                       const float* __restrict__ b1, const float* __restrict__ W2,
                       __half* __restrict__ ht2, int n) {
  __shared__ float sw2[256];
  __shared__ float sr[32][18];
  int tid = threadIdx.x;
  sw2[tid] = W2[tid];
  int g = tid >> 3, s = tid & 7;
  int node = blockIdx.x * 32 + g;
  float a0 = 0.f, a1 = 0.f, di = 0.f;
  if (node < n) {
    u32 e0 = rowptr[node], e1 = rowptr[node + 1];
    edge_sum2(ht1, csr, e0, e1, s, a0, a1);
    di = dinv[node];
    u32 hs = *(const u32*)((const char*)ht1 + (size_t)node * 32 + s * 4);
    float2 sf = __half22float2(*(__half2*)&hs);
    a0 = fmaxf(di * (a0 + sf.x) + b1[2 * s + 0], 0.f);
    a1 = fmaxf(di * (a1 + sf.y) + b1[2 * s + 1], 0.f);
  }
  sr[g][2 * s] = a0; sr[g][2 * s + 1] = a1;
  __syncthreads();
  if (node < n) {
    float o0 = 0.f, o1 = 0.f;
    #pragma unroll
    for (int k = 0; k < 16; k++) {
      float hk = sr[g][k];
      o0 += hk * sw2[k * 16 + 2 * s];
      o1 += hk * sw2[k * 16 + 2 * s + 1];
    }
    __half2 p = __floats2half2_rn(di * o0, di * o1);
    *(u32*)((char*)ht2 + (size_t)node * 32 + s * 4) = *(u32*)&p;
  }
}

// Conv2 agg + bias, fused mean-pool partials (segmented LDS reduce + native f32 atomics).
__global__ void k_agg2(const __half* __restrict__ ht2, const u32* __restrict__ rowptr,
                       const uint2* __restrict__ csr, const float* __restrict__ dinv,
                       const float* __restrict__ b2, const int* __restrict__ batch,
                       float* __restrict__ pooled, int n) {
  __shared__ float sr[32][18];
  __shared__ int sbid[32];
  int tid = threadIdx.x;
  int g = tid >> 3, s = tid & 7;
  int node = blockIdx.x * 32 + g;
  float a0 = 0.f, a1 = 0.f;
  int myb = -1;
  if (node < n) {
    u32 e0 = rowptr[node], e1 = rowptr[node + 1];
    edge_sum2(ht2, csr, e0, e1, s, a0, a1);
    float di = dinv[node];
    u32 hs = *(const u32*)((const char*)ht2 + (size_t)node * 32 + s * 4);
    float2 sf = __half22float2(*(__half2*)&hs);
    a0 = di * (a0 + sf.x) + b2[2 * s + 0];
    a1 = di * (a1 + sf.y) + b2[2 * s + 1];
    myb = batch[node];
  }
  sr[g][2 * s] = a0; sr[g][2 * s + 1] = a1;
  if (s == 0) sbid[g] = myb;
  __syncthreads();
  if (node < n) {
    bool head = (g == 0) || (sbid[g - 1] != myb);
    if (head) {
      float s0 = a0, s1 = a1;
      for (int t = g + 1; t < 32 && sbid[t] == myb; t++) {
        s0 += sr[t][2 * s]; s1 += sr[t][2 * s + 1];
      }
      float* pb = &pooled[(size_t)myb * 16 + 2 * s];
      unsafeAtomicAdd(pb + 0, s0);
      unsafeAtomicAdd(pb + 1, s1);
    }
  }
}

// Mean + FC. Graph sizes via binary search on sorted batch.
__global__ void k_final(const float* __restrict__ pooled, const int* __restrict__ batch,
                        const float* __restrict__ fcW, const float* __restrict__ fcb,
                        float* __restrict__ out, int n, int G) {
  int g = blockIdx.x * blockDim.x + threadIdx.x;
  if (g >= G) return;
  int lo = 0, hi = n;
  while (lo < hi) { int m = (lo + hi) >> 1; if (batch[m] < g) lo = m + 1; else hi = m; }
  int lo2 = lo, hi2 = n;
  while (lo2 < hi2) { int m = (lo2 + hi2) >> 1; if (batch[m] < g + 1) lo2 = m + 1; else hi2 = m; }
  float c = (float)(lo2 - lo);
  float inv = 1.0f / fmaxf(c, 1.0f);
  float s = 0.f;
  #pragma unroll
  for (int j = 0; j < 16; j++) s += pooled[g * 16 + j] * fcW[j];
  out[g] = s * inv + fcb[0];
}

extern "C" void kernel_launch(void* const* d_in, const int* in_sizes, int n_in,
                              void* d_out, int out_size, void* d_ws, size_t ws_size,
                              hipStream_t stream) {
  const float* x    = (const float*)d_in[0];
  const int*   ei   = (const int*)d_in[1];
  const float* ew   = (const float*)d_in[2];
  const int*   batch= (const int*)d_in[3];
  const float* W1   = (const float*)d_in[4];
  const float* b1   = (const float*)d_in[5];
  const float* W2   = (const float*)d_in[6];
  const float* b2   = (const float*)d_in[7];
  const float* fcW  = (const float*)d_in[8];
  const float* fcb  = (const float*)d_in[9];
  float* out = (float*)d_out;

  int N = in_sizes[3];
  int E = in_sizes[2];
  int G = out_size;
  const int* row = ei;     // edge_index[0] = source
  const int* col = ei + E; // edge_index[1] = target

  int C   = (N + 4095) >> CSH;   // 25 coarse buckets
  int NBF = C * FPB;             // 800 fine buckets
  int chunk1 = (((E + NBLK1 - 1) / NBLK1) + 1) & ~1;   // even, for int2 loads

  char* w = (char*)d_ws;
  size_t off = 0;
  auto alloc = [&](size_t bytes) -> char* { char* p = w + off; off = al16(off + bytes); return p; };
  u32*   hist1   = (u32*)  alloc((size_t)NBLK1 * C * 4);
  u32*   hofs1   = (u32*)  alloc((size_t)C * NBLK1 * 4);
  u32*   totals1 = (u32*)  alloc((size_t)C * 4);
  u32*   bstart1 = (u32*)  alloc(((size_t)C + 1) * 4);
  u32*   cnt2    = (u32*)  alloc((size_t)C * K2 * FPB * 4);
  u32*   hofs2   = (u32*)  alloc((size_t)C * FPB * K2 * 4);
  u32*   bstart2 = (u32*)  alloc(((size_t)NBF + 1) * 4);
  u32*   rowptr  = (u32*)  alloc(((size_t)N + 1) * 4);
  float* dinv    = (float*)alloc((size_t)N * 4);
  u8*    fid     = (u8*)   alloc((size_t)E);
  uint2* recs1   = (uint2*)alloc((size_t)E * 8);
  uint2* recs2   = (uint2*)alloc((size_t)E * 8);
  float* pooled  = (float*)alloc((size_t)G * 16 * 4);
  // Aliases: csr overlays recs1 (dead after part2); ht1/ht2 overlay recs2 (dead after build).
  uint2*  csr = recs1;
  __half* ht1 = (__half*)recs2;
  __half* ht2 = (__half*)((char*)recs2 + (size_t)N * 16 * 2);
  (void)n_in; (void)ws_size;

  int nb = (N + 255) / 256;
  int ab = (N + 31) / 32;
  int gb = (G + 255) / 256;

  k_hist1 <<<NBLK1, 512, 0, stream>>>(col, hist1, pooled, rowptr, G * 16, N, E, C, chunk1);
  k_cscan1<<<C, NBLK1, 0, stream>>>(hist1, hofs1, totals1, C);
  k_part1 <<<NBLK1, 512, 0, stream>>>(row, col, ew, totals1, bstart1, hofs1, recs1, fid, E, C, chunk1);
  k_hist2 <<<C * K2, 1024, 0, stream>>>(fid, bstart1, cnt2);
  k_cscan2<<<C, 512, 0, stream>>>(cnt2, bstart1, hofs2, bstart2, C, E);
  k_part2 <<<C * K2, 1024, 0, stream>>>(recs1, bstart1, hofs2, bstart2, recs2);
  k_build <<<NBF, 256, 0, stream>>>(recs2, bstart2, rowptr, csr, dinv, N);
  k_gemm1 <<<nb, 256, 0, stream>>>(x, W1, dinv, ht1, N);
  k_agg1  <<<ab, 256, 0, stream>>>(ht1, rowptr, csr, dinv, b1, W2, ht2, N);
  k_agg2  <<<ab, 256, 0, stream>>>(ht2, rowptr, csr, dinv, b2, batch, pooled, N);
  k_final <<<gb, 256, 0, stream>>>(pooled, batch, fcW, fcb, out, N, G);
}

// Round 15
// 145.369 us; speedup vs baseline: 1.6085x; 1.1145x over previous
//
#include <hip/hip_runtime.h>
#include <hip/hip_fp16.h>

typedef unsigned int u32;
typedef unsigned char u8;

static inline size_t al16(size_t x){ return (x + 15) & ~(size_t)15; }

#define CSH 12             // 4096 nodes per coarse bucket
#define NBLK1 512          // level-1 partition blocks
#define K2 16              // level-2 chunks per coarse region
#define FPB 32             // fine buckets per coarse (4096/128)
#define NPB 128            // nodes per fine bucket
#define PBSH 7
#define SRCMSK 0xFFFFFu
#define STAGE_CAP 5120     // packed-u32 staging per fine bucket (20KB LDS)
#define REG_E 16           // edges staged in registers per thread (covers 4096/bucket)

// csr packing: {src:17 bits [31:15] | (fp16_bits(w)>>1):15 bits [14:0]} (w>=0 -> sign 0)
__device__ __forceinline__ u32 pack_edge(u32 src, float w) {
  u32 wb = (u32)__half_as_ushort(__float2half(w));
  return (src << 15) | (wb >> 1);
}
__device__ __forceinline__ float unpack_w(u32 p) {
  return __half2float(__ushort_as_half((unsigned short)(p << 1)));
}

// L1 hist: per-block LDS histogram of coarse buckets, 2 edges/thread.
// Block 0 also zeroes pooled and sets rowptr[N] sentinel.
__global__ void k_hist1(const int* __restrict__ col, u32* __restrict__ hist1,
                        float* __restrict__ pooled, u32* __restrict__ rowptr,
                        int PG, int N, int E, int C, int chunk) {
  __shared__ u32 h[64];
  int tid = threadIdx.x, blk = blockIdx.x;
  if (blk == 0) {
    for (int i = tid; i < PG; i += 512) pooled[i] = 0.f;
    if (tid == 0) rowptr[N] = (u32)E;
  }
  if (tid < 64) h[tid] = 0;
  __syncthreads();
  int e0 = blk * chunk, e1 = min(E, e0 + chunk);
  for (int e = e0 + 2 * tid; e < e1; e += 1024) {
    if (e + 1 < e1) {
      int2 cc = *(const int2*)(col + e);
      atomicAdd(&h[cc.x >> CSH], 1u);
      atomicAdd(&h[cc.y >> CSH], 1u);
    } else {
      atomicAdd(&h[col[e] >> CSH], 1u);
    }
  }
  __syncthreads();
  if (tid < C) hist1[(size_t)blk * C + tid] = h[tid];
}

// L1 scan: per coarse bucket, exclusive scan over NBLK1 blocks.
__global__ void k_cscan1(const u32* __restrict__ hist1, u32* __restrict__ hofs1,
                         u32* __restrict__ totals1, int C) {
  __shared__ u32 s[NBLK1];
  int i = blockIdx.x, t = threadIdx.x;
  u32 v = hist1[(size_t)t * C + i];
  s[t] = v; __syncthreads();
  for (int off = 1; off < NBLK1; off <<= 1) {
    u32 x = (t >= off) ? s[t - off] : 0u;
    __syncthreads(); s[t] += x; __syncthreads();
  }
  hofs1[(size_t)i * NBLK1 + t] = s[t] - v;
  if (t == NBLK1 - 1) totals1[i] = s[t];
}

// L1 scatter, 2 edges/thread. Bucket bases from totals1 in-block; block 0
// materializes bstart1.
__global__ void k_part1(const int* __restrict__ row, const int* __restrict__ col,
                        const float* __restrict__ ew, const u32* __restrict__ totals1,
                        u32* __restrict__ bstart1, const u32* __restrict__ hofs1,
                        uint2* __restrict__ recs1, u8* __restrict__ fid,
                        int E, int C, int chunk) {
  __shared__ u32 cur[64];
  __shared__ u32 bs[64];
  int tid = threadIdx.x, blk = blockIdx.x;
  if (tid == 0) {
    u32 a = 0;
    for (int i = 0; i < C; i++) { bs[i] = a; a += totals1[i]; }
    if (blk == 0) {
      for (int i = 0; i < C; i++) bstart1[i] = bs[i];
      bstart1[C] = (u32)E;
    }
  }
  __syncthreads();
  if (tid < C) cur[tid] = bs[tid] + hofs1[(size_t)tid * NBLK1 + blk];
  __syncthreads();
  int e0 = blk * chunk, e1 = min(E, e0 + chunk);
  for (int e = e0 + 2 * tid; e < e1; e += 1024) {
    int2 rr, cc; float2 wv;
    bool two = (e + 1 < e1);
    if (two) {
      rr = *(const int2*)(row + e);
      cc = *(const int2*)(col + e);
      wv = *(const float2*)(ew + e);
    } else {
      rr.x = row[e]; cc.x = col[e]; wv.x = ew[e];
      rr.y = 0; cc.y = 0; wv.y = 0.f;
    }
    {
      int c = cc.x, cb = c >> CSH;
      u32 dl12 = (u32)(c & 4095);
      u32 pos = atomicAdd(&cur[cb], 1u);
      uint2 v; v.x = (u32)rr.x | (dl12 << 20); v.y = __float_as_uint(wv.x);
      recs1[pos] = v;
      fid[pos] = (u8)(dl12 >> PBSH);
    }
    if (two) {
      int c = cc.y, cb = c >> CSH;
      u32 dl12 = (u32)(c & 4095);
      u32 pos = atomicAdd(&cur[cb], 1u);
      uint2 v; v.x = (u32)rr.y | (dl12 << 20); v.y = __float_as_uint(wv.y);
      recs1[pos] = v;
      fid[pos] = (u8)(dl12 >> PBSH);
    }
  }
}

// L2 hist: block (cb,k); 32 fine-bucket counters from the 1B fid stream.
__global__ void k_hist2(const u8* __restrict__ fid, const u32* __restrict__ bstart1,
                        u32* __restrict__ cnt2) {
  __shared__ u32 h[FPB];
  int cb = blockIdx.x >> 4, k = blockIdx.x & 15;
  int t = threadIdx.x;
  if (t < FPB) h[t] = 0;
  __syncthreads();
  u32 r0 = bstart1[cb], r1 = bstart1[cb + 1];
  u32 len = r1 - r0, ch = (len + K2 - 1) / K2;
  u32 e0 = r0 + (u32)k * ch, e1 = min(r1, e0 + ch);
  for (u32 e = e0 + t; e < e1; e += 1024) atomicAdd(&h[fid[e]], 1u);
  __syncthreads();
  if (t < FPB) cnt2[((size_t)cb * K2 + k) * FPB + t] = h[t];
}

// L2 scan -> hofs2[cb][f][k], bstart2[cb*32+f].
__global__ void k_cscan2(const u32* __restrict__ cnt2, const u32* __restrict__ bstart1,
                         u32* __restrict__ hofs2, u32* __restrict__ bstart2,
                         int C, int E) {
  __shared__ u32 s[512];
  __shared__ u32 sx[512];
  int cb = blockIdx.x, t = threadIdx.x;
  int f = t >> 4, k = t & 15;
  u32 v = cnt2[((size_t)cb * K2 + k) * FPB + f];
  s[t] = v; __syncthreads();
  for (int off = 1; off < 512; off <<= 1) {
    u32 x = (t >= off) ? s[t - off] : 0u;
    __syncthreads(); s[t] += x; __syncthreads();
  }
  sx[t] = s[t] - v;
  __syncthreads();
  hofs2[((size_t)cb * FPB + f) * K2 + k] = sx[t] - sx[f << 4];
  if (k == 0) bstart2[cb * FPB + f] = bstart1[cb] + sx[t];
  if (cb == C - 1 && t == 0) bstart2[C * FPB] = (u32)E;
}

// L2 scatter: fine-bucket-contiguous recs2. 32 LDS cursors.
__global__ void k_part2(const uint2* __restrict__ recs1, const u32* __restrict__ bstart1,
                        const u32* __restrict__ hofs2, const u32* __restrict__ bstart2,
                        uint2* __restrict__ recs2) {
  __shared__ u32 cur[FPB];
  int cb = blockIdx.x >> 4, k = blockIdx.x & 15;
  int t = threadIdx.x;
  if (t < FPB) cur[t] = bstart2[cb * FPB + t] + hofs2[((size_t)cb * FPB + t) * K2 + k];
  __syncthreads();
  u32 r0 = bstart1[cb], r1 = bstart1[cb + 1];
  u32 len = r1 - r0, ch = (len + K2 - 1) / K2;
  u32 e0 = r0 + (u32)k * ch, e1 = min(r1, e0 + ch);
  for (u32 e = e0 + t; e < e1; e += 1024) {
    uint2 v = recs1[e];
    u32 pos = atomicAdd(&cur[v.x >> 27], 1u);
    recs2[pos] = v;
  }
}

// Build: one block per fine bucket. recs2 read ONCE into registers (16/thread,
// global fallback past 4096), count -> scan -> packed-u32 LDS stage sort ->
// coalesced 4B csr write-out + rowptr + fused deg (fp15 w) -> dinv.
__global__ void k_build(const uint2* __restrict__ recs2, const u32* __restrict__ bstart2,
                        u32* __restrict__ rowptr, u32* __restrict__ csr,
                        float* __restrict__ dinv, int N) {
  __shared__ u32 stage[STAGE_CAP];
  __shared__ u32 cnt[NPB];
  __shared__ u32 sc[NPB];
  __shared__ u32 cur[NPB];
  int b = blockIdx.x, t = threadIdx.x;
  if (t < NPB) cnt[t] = 0;
  __syncthreads();
  u32 r0 = bstart2[b], r1 = bstart2[b + 1];
  u32 len = r1 - r0;
  u32 nreg = min(len, (u32)(REG_E * 256));
  int cap_ok = len <= STAGE_CAP;
  uint2 myrec[REG_E];
  #pragma unroll
  for (int i = 0; i < REG_E; i++) {
    u32 e = r0 + (u32)t + (u32)i * 256u;
    if (e < r0 + nreg) {
      myrec[i] = recs2[e];
      atomicAdd(&cnt[(myrec[i].x >> 20) & 127], 1u);
    }
  }
  for (u32 e = r0 + nreg + t; e < r1; e += 256) atomicAdd(&cnt[(recs2[e].x >> 20) & 127], 1u);
  __syncthreads();
  if (t < NPB) sc[t] = cnt[t];
  __syncthreads();
  for (int off = 1; off < NPB; off <<= 1) {
    u32 x = (t < NPB && t >= off) ? sc[t - off] : 0u;
    __syncthreads();
    if (t < NPB) sc[t] += x;
    __syncthreads();
  }
  if (t < NPB) {
    u32 excl = sc[t] - cnt[t];
    int node = (b << PBSH) + t;
    if (node < N) rowptr[node] = r0 + excl;
    cur[t] = excl;
  }
  __syncthreads();
  if (cap_ok) {
    #pragma unroll
    for (int i = 0; i < REG_E; i++) {
      u32 e = r0 + (u32)t + (u32)i * 256u;
      if (e < r0 + nreg) {
        u32 dl = (myrec[i].x >> 20) & 127;
        u32 slot = atomicAdd(&cur[dl], 1u);
        stage[slot] = pack_edge(myrec[i].x & SRCMSK, __uint_as_float(myrec[i].y));
      }
    }
    for (u32 e = r0 + nreg + t; e < r1; e += 256) {
      uint2 v = recs2[e];
      u32 dl = (v.x >> 20) & 127;
      u32 slot = atomicAdd(&cur[dl], 1u);
      stage[slot] = pack_edge(v.x & SRCMSK, __uint_as_float(v.y));
    }
    __syncthreads();
    for (u32 i = t; i < len; i += 256) csr[r0 + i] = stage[i];
    if (t < NPB) {
      int node = (b << PBSH) + t;
      if (node < N) {
        u32 base = sc[t] - cnt[t], c = cnt[t];
        float sd = 0.f;
        for (u32 i = 0; i < c; i++) sd += unpack_w(stage[base + i]);
        dinv[node] = rsqrtf(sd + 1.0f);   // +1 = self-loop weight
      }
    }
  } else {
    // statistically-never fallback: direct packed scatter + deg from global
    #pragma unroll
    for (int i = 0; i < REG_E; i++) {
      u32 e = r0 + (u32)t + (u32)i * 256u;
      if (e < r0 + nreg) {
        u32 dl = (myrec[i].x >> 20) & 127;
        u32 slot = atomicAdd(&cur[dl], 1u);
        csr[r0 + slot] = pack_edge(myrec[i].x & SRCMSK, __uint_as_float(myrec[i].y));
      }
    }
    for (u32 e = r0 + nreg + t; e < r1; e += 256) {
      uint2 v = recs2[e];
      u32 dl = (v.x >> 20) & 127;
      u32 slot = atomicAdd(&cur[dl], 1u);
      csr[r0 + slot] = pack_edge(v.x & SRCMSK, __uint_as_float(v.y));
    }
    __syncthreads();
    if (t < NPB) {
      int node = (b << PBSH) + t;
      if (node < N) {
        u32 base = r0 + sc[t] - cnt[t], c = cnt[t];
        float sd = 0.f;
        for (u32 i = 0; i < c; i++) sd += unpack_w(csr[base + i]);
        dinv[node] = rsqrtf(sd + 1.0f);
      }
    }
  }
}

// ht1' = dinv[node] * (x @ W1), fp16 node-major.
__global__ void k_gemm1(const float* __restrict__ x, const float* __restrict__ W1,
                        const float* __restrict__ dinv, __half* __restrict__ ht1, int n) {
  __shared__ float sw[2048];
  for (int i = threadIdx.x; i < 2048; i += blockDim.x) sw[i] = W1[i];
  __syncthreads();
  int node = blockIdx.x * blockDim.x + threadIdx.x;
  if (node >= n) return;
  const float4* xr = (const float4*)(x + (size_t)node * 128);
  float acc[16];
  #pragma unroll
  for (int j = 0; j < 16; j++) acc[j] = 0.f;
  #pragma unroll 4
  for (int k4 = 0; k4 < 32; k4++) {
    float4 xv = xr[k4];
    const float* wb = &sw[k4 * 64];
    #pragma unroll
    for (int j = 0; j < 16; j++) acc[j] += xv.x * wb[j];
    #pragma unroll
    for (int j = 0; j < 16; j++) acc[j] += xv.y * wb[16 + j];
    #pragma unroll
    for (int j = 0; j < 16; j++) acc[j] += xv.z * wb[32 + j];
    #pragma unroll
    for (int j = 0; j < 16; j++) acc[j] += xv.w * wb[48 + j];
  }
  float di = dinv[node];
  u32 o[8];
  #pragma unroll
  for (int p = 0; p < 8; p++) {
    u32 lo = (u32)__half_as_ushort(__float2half(di * acc[2 * p]));
    u32 hi = (u32)__half_as_ushort(__float2half(di * acc[2 * p + 1]));
    o[p] = lo | (hi << 16);
  }
  uint4* dst = (uint4*)(ht1 + (size_t)node * 16);
  dst[0] = make_uint4(o[0], o[1], o[2], o[3]);
  dst[1] = make_uint4(o[4], o[5], o[6], o[7]);
}

// Per-edge core, 8 lanes/node, packed 4B csr: ONE shuffle per edge (LDS-pipe
// bound halved vs 8B records). 16-edge double batches for ILP.
__device__ __forceinline__ void edge_sum2(const __half* __restrict__ ht,
                                          const u32* __restrict__ csr,
                                          u32 e0, u32 e1, int s,
                                          float& a0, float& a1) {
  float b0 = 0.f, b1 = 0.f;
  u32 e = e0;
  for (; e + 16 <= e1; e += 16) {
    u32 pA = csr[e + (u32)s];
    u32 pB = csr[e + 8 + (u32)s];
    #pragma unroll
    for (int t = 0; t < 8; t++) {
      u32 qA = (u32)__shfl((int)pA, t, 8);
      u32 qB = (u32)__shfl((int)pB, t, 8);
      float wA = unpack_w(qA);
      float wB = unpack_w(qB);
      u32 hA = *(const u32*)((const char*)ht + (size_t)(qA >> 15) * 32 + s * 4);
      u32 hB = *(const u32*)((const char*)ht + (size_t)(qB >> 15) * 32 + s * 4);
      float2 fA = __half22float2(*(__half2*)&hA);
      float2 fB = __half22float2(*(__half2*)&hB);
      a0 += wA * fA.x; a1 += wA * fA.y;
      b0 += wB * fB.x; b1 += wB * fB.y;
    }
  }
  for (; e < e1; e += 8) {
    u32 idx = e + (u32)s;
    u32 p = (idx < e1) ? csr[idx] : 0u;   // pad: src=0, w=+0
    #pragma unroll
    for (int t = 0; t < 8; t++) {
      u32 q = (u32)__shfl((int)p, t, 8);
      float wt = unpack_w(q);
      u32 hw = *(const u32*)((const char*)ht + (size_t)(q >> 15) * 32 + s * 4);
      float2 hf = __half22float2(*(__half2*)&hw);
      a0 += wt * hf.x;
      a1 += wt * hf.y;
    }
  }
  a0 += b0; a1 += b1;
}

// Conv1 agg + bias + relu, fused @W2; epilogue scales by dinv for agg2's table.
__global__ void k_agg1(const __half* __restrict__ ht1, const u32* __restrict__ rowptr,
                       const u32* __restrict__ csr, const float* __restrict__ dinv,
                       const float* __restrict__ b1, const float* __restrict__ W2,
                       __half* __restrict__ ht2, int n) {
  __shared__ float sw2[256];
  __shared__ float sr[32][18];
  int tid = threadIdx.x;
  sw2[tid] = W2[tid];
  int g = tid >> 3, s = tid & 7;
  int node = blockIdx.x * 32 + g;
  float a0 = 0.f, a1 = 0.f, di = 0.f;
  if (node < n) {
    u32 e0 = rowptr[node], e1 = rowptr[node + 1];
    edge_sum2(ht1, csr, e0, e1, s, a0, a1);
    di = dinv[node];
    u32 hs = *(const u32*)((const char*)ht1 + (size_t)node * 32 + s * 4);
    float2 sf = __half22float2(*(__half2*)&hs);
    a0 = fmaxf(di * (a0 + sf.x) + b1[2 * s + 0], 0.f);
    a1 = fmaxf(di * (a1 + sf.y) + b1[2 * s + 1], 0.f);
  }
  sr[g][2 * s] = a0; sr[g][2 * s + 1] = a1;
  __syncthreads();
  if (node < n) {
    float o0 = 0.f, o1 = 0.f;
    #pragma unroll
    for (int k = 0; k < 16; k++) {
      float hk = sr[g][k];
      o0 += hk * sw2[k * 16 + 2 * s];
      o1 += hk * sw2[k * 16 + 2 * s + 1];
    }
    __half2 p = __floats2half2_rn(di * o0, di * o1);
    *(u32*)((char*)ht2 + (size_t)node * 32 + s * 4) = *(u32*)&p;
  }
}

// Conv2 agg + bias, fused mean-pool partials (segmented LDS reduce + native f32 atomics).
__global__ void k_agg2(const __half* __restrict__ ht2, const u32* __restrict__ rowptr,
                       const u32* __restrict__ csr, const float* __restrict__ dinv,
                       const float* __restrict__ b2, const int* __restrict__ batch,
                       float* __restrict__ pooled, int n) {
  __shared__ float sr[32][18];
  __shared__ int sbid[32];
  int tid = threadIdx.x;
  int g = tid >> 3, s = tid & 7;
  int node = blockIdx.x * 32 + g;
  float a0 = 0.f, a1 = 0.f;
  int myb = -1;
  if (node < n) {
    u32 e0 = rowptr[node], e1 = rowptr[node + 1];
    edge_sum2(ht2, csr, e0, e1, s, a0, a1);
    float di = dinv[node];
    u32 hs = *(const u32*)((const char*)ht2 + (size_t)node * 32 + s * 4);
    float2 sf = __half22float2(*(__half2*)&hs);
    a0 = di * (a0 + sf.x) + b2[2 * s + 0];
    a1 = di * (a1 + sf.y) + b2[2 * s + 1];
    myb = batch[node];
  }
  sr[g][2 * s] = a0; sr[g][2 * s + 1] = a1;
  if (s == 0) sbid[g] = myb;
  __syncthreads();
  if (node < n) {
    bool head = (g == 0) || (sbid[g - 1] != myb);
    if (head) {
      float s0 = a0, s1 = a1;
      for (int t = g + 1; t < 32 && sbid[t] == myb; t++) {
        s0 += sr[t][2 * s]; s1 += sr[t][2 * s + 1];
      }
      float* pb = &pooled[(size_t)myb * 16 + 2 * s];
      unsafeAtomicAdd(pb + 0, s0);
      unsafeAtomicAdd(pb + 1, s1);
    }
  }
}

// Mean + FC. Graph sizes via binary search on sorted batch.
__global__ void k_final(const float* __restrict__ pooled, const int* __restrict__ batch,
                        const float* __restrict__ fcW, const float* __restrict__ fcb,
                        float* __restrict__ out, int n, int G) {
  int g = blockIdx.x * blockDim.x + threadIdx.x;
  if (g >= G) return;
  int lo = 0, hi = n;
  while (lo < hi) { int m = (lo + hi) >> 1; if (batch[m] < g) lo = m + 1; else hi = m; }
  int lo2 = lo, hi2 = n;
  while (lo2 < hi2) { int m = (lo2 + hi2) >> 1; if (batch[m] < g + 1) lo2 = m + 1; else hi2 = m; }
  float c = (float)(lo2 - lo);
  float inv = 1.0f / fmaxf(c, 1.0f);
  float s = 0.f;
  #pragma unroll
  for (int j = 0; j < 16; j++) s += pooled[g * 16 + j] * fcW[j];
  out[g] = s * inv + fcb[0];
}

extern "C" void kernel_launch(void* const* d_in, const int* in_sizes, int n_in,
                              void* d_out, int out_size, void* d_ws, size_t ws_size,
                              hipStream_t stream) {
  const float* x    = (const float*)d_in[0];
  const int*   ei   = (const int*)d_in[1];
  const float* ew   = (const float*)d_in[2];
  const int*   batch= (const int*)d_in[3];
  const float* W1   = (const float*)d_in[4];
  const float* b1   = (const float*)d_in[5];
  const float* W2   = (const float*)d_in[6];
  const float* b2   = (const float*)d_in[7];
  const float* fcW  = (const float*)d_in[8];
  const float* fcb  = (const float*)d_in[9];
  float* out = (float*)d_out;

  int N = in_sizes[3];
  int E = in_sizes[2];
  int G = out_size;
  const int* row = ei;     // edge_index[0] = source
  const int* col = ei + E; // edge_index[1] = target

  int C   = (N + 4095) >> CSH;   // 25 coarse buckets
  int NBF = C * FPB;             // 800 fine buckets
  int chunk1 = (((E + NBLK1 - 1) / NBLK1) + 1) & ~1;   // even, for int2 loads

  char* w = (char*)d_ws;
  size_t off = 0;
  auto alloc = [&](size_t bytes) -> char* { char* p = w + off; off = al16(off + bytes); return p; };
  u32*   hist1   = (u32*)  alloc((size_t)NBLK1 * C * 4);
  u32*   hofs1   = (u32*)  alloc((size_t)C * NBLK1 * 4);
  u32*   totals1 = (u32*)  alloc((size_t)C * 4);
  u32*   bstart1 = (u32*)  alloc(((size_t)C + 1) * 4);
  u32*   cnt2    = (u32*)  alloc((size_t)C * K2 * FPB * 4);
  u32*   hofs2   = (u32*)  alloc((size_t)C * FPB * K2 * 4);
  u32*   bstart2 = (u32*)  alloc(((size_t)NBF + 1) * 4);
  u32*   rowptr  = (u32*)  alloc(((size_t)N + 1) * 4);
  float* dinv    = (float*)alloc((size_t)N * 4);
  u8*    fid     = (u8*)   alloc((size_t)E);
  uint2* recs1   = (uint2*)alloc((size_t)E * 8);
  uint2* recs2   = (uint2*)alloc((size_t)E * 8);
  float* pooled  = (float*)alloc((size_t)G * 16 * 4);
  // Aliases: csr (4B packed) overlays recs1 (dead after part2); ht1/ht2 overlay
  // recs2 (dead after build).
  u32*    csr = (u32*)recs1;
  __half* ht1 = (__half*)recs2;
  __half* ht2 = (__half*)((char*)recs2 + (size_t)N * 16 * 2);
  (void)n_in; (void)ws_size;

  int nb = (N + 255) / 256;
  int ab = (N + 31) / 32;
  int gb = (G + 255) / 256;

  k_hist1 <<<NBLK1, 512, 0, stream>>>(col, hist1, pooled, rowptr, G * 16, N, E, C, chunk1);
  k_cscan1<<<C, NBLK1, 0, stream>>>(hist1, hofs1, totals1, C);
  k_part1 <<<NBLK1, 512, 0, stream>>>(row, col, ew, totals1, bstart1, hofs1, recs1, fid, E, C, chunk1);
  k_hist2 <<<C * K2, 1024, 0, stream>>>(fid, bstart1, cnt2);
  k_cscan2<<<C, 512, 0, stream>>>(cnt2, bstart1, hofs2, bstart2, C, E);
  k_part2 <<<C * K2, 1024, 0, stream>>>(recs1, bstart1, hofs2, bstart2, recs2);
  k_build <<<NBF, 256, 0, stream>>>(recs2, bstart2, rowptr, csr, dinv, N);
  k_gemm1 <<<nb, 256, 0, stream>>>(x, W1, dinv, ht1, N);
  k_agg1  <<<ab, 256, 0, stream>>>(ht1, rowptr, csr, dinv, b1, W2, ht2, N);
  k_agg2  <<<ab, 256, 0, stream>>>(ht2, rowptr, csr, dinv, b2, batch, pooled, N);
  k_final <<<gb, 256, 0, stream>>>(pooled, batch, fcW, fcb, out, N, G);
}